// Round 5
// baseline (666.670 us; speedup 1.0000x reference)
//
#include <hip/hip_runtime.h>
#include <hip/hip_bf16.h>
#include <stdint.h>

// Problem constants
#define A_N 8
#define B_N 32768
#define IN_N 128
#define OUT_N 32
#define SAF 160      // IN + OUT  (= enc K, exactly 5 x 32: NO pad)
#define H_N 128
#define D_N 32
#define KD_N 128     // K*D
#define CIN_N 256    // critic input = H + K*D
#define CHUNKS 128   // stats chunks over B
#define EPSV 1e-5f

typedef unsigned int u32;
typedef unsigned short u16;
typedef __attribute__((ext_vector_type(8))) short short8;    // 8 bf16 (4 VGPRs)
typedef __attribute__((ext_vector_type(4))) float floatx4;   // MFMA C/D

// async global->LDS, 16B per lane. LDS dest = wave-uniform base + lane*16,
// so dest layout MUST be linear in lane order; source kept linear too
// (R3 showed permuted sources defeat VMEM coalescing). Weight tiles are
// packed tile-major [k-tile][128 n][32 k] so linear glds lands correctly.
// NOTE (R2-R4): LDS XOR-swizzle of these tiles cut SQ_LDS_BANK_CONFLICT
// 6.4M->2.75M but was NET ZERO on wall clock across 3 rounds -- conflicts
// are ~1-2% of kernel time here. Reverted to linear everywhere.
typedef __attribute__((address_space(1))) void gvoid;
typedef __attribute__((address_space(3))) void lvoid;
__device__ __forceinline__ void glds16(const void* g, void* l){
  __builtin_amdgcn_global_load_lds((gvoid*)g, (lvoid*)l, 16, 0, 0);
}

__device__ __forceinline__ float bf_lo(u32 u){ return __uint_as_float(u << 16); }
__device__ __forceinline__ float bf_hi(u32 u){ return __uint_as_float(u & 0xffff0000u); }
__device__ __forceinline__ float bf2f(u16 b){ return __uint_as_float(((u32)b) << 16); }
__device__ __forceinline__ u16 f2bf(float f){
  u32 u = __float_as_uint(f);
  return (u16)((u + 0x7fffu + ((u >> 16) & 1u)) >> 16);
}
__device__ __forceinline__ float lrelu(float x){ return x > 0.f ? x : 0.01f * x; }

// ---------------------------------------------------------------------------
// Stage 1: BN statistics (sum, sumsq) per (agent, feature).
// ---------------------------------------------------------------------------
__global__ __launch_bounds__(256) void k_stats(
    const float* __restrict__ states, const float* __restrict__ actions,
    float* __restrict__ part)
{
  int a = blockIdx.y;
  int chunk = blockIdx.x;
  int t = threadIdx.x;
  int r0 = chunk * (B_N / CHUNKS);   // 256 rows per chunk
  __shared__ float red[512];
  {
    int f = t & 127, half = t >> 7;
    const float* p = states + ((size_t)a * B_N + r0 + half) * IN_N + f;
    float s1 = 0.f, s2 = 0.f;
    for (int it = 0; it < 128; ++it){
      float v = p[(size_t)(2 * it) * IN_N];
      s1 += v; s2 += v * v;
    }
    red[t] = s1; red[256 + t] = s2;
    __syncthreads();
    if (t < 128){
      float a1 = red[t] + red[t + 128];
      float a2 = red[256 + t] + red[256 + t + 128];
      size_t o = (((size_t)a * CHUNKS + chunk) * SAF + t) * 2;
      part[o] = a1; part[o + 1] = a2;
    }
    __syncthreads();
  }
  {
    int f = t & 31, g = t >> 5;
    const float* p = actions + ((size_t)a * B_N + r0 + g) * OUT_N + f;
    float s1 = 0.f, s2 = 0.f;
    for (int it = 0; it < 32; ++it){
      float v = p[(size_t)(8 * it) * OUT_N];
      s1 += v; s2 += v * v;
    }
    red[t] = s1; red[256 + t] = s2;
    __syncthreads();
    if (t < 32){
      float a1 = 0.f, a2 = 0.f;
      #pragma unroll
      for (int gg = 0; gg < 8; ++gg){
        a1 += red[t + 32 * gg];
        a2 += red[256 + t + 32 * gg];
      }
      size_t o = (((size_t)a * CHUNKS + chunk) * SAF + 128 + t) * 2;
      part[o] = a1; part[o + 1] = a2;
    }
  }
}

__global__ void k_finalize(const float* __restrict__ part,
                           float* __restrict__ meanArr, float* __restrict__ istdArr)
{
  int idx = blockIdx.x * blockDim.x + threadIdx.x;
  if (idx >= A_N * SAF) return;
  int a = idx / SAF, f = idx % SAF;
  float s1 = 0.f, s2 = 0.f;
  for (int c = 0; c < CHUNKS; ++c){
    size_t o = (((size_t)a * CHUNKS + c) * SAF + f) * 2;
    s1 += part[o]; s2 += part[o + 1];
  }
  float m = s1 * (1.f / B_N);
  float v = s2 * (1.f / B_N) - m * m;
  if (v < 0.f) v = 0.f;
  meanArr[idx] = m;
  istdArr[idx] = rsqrtf(v + EPSV);
}

// ---------------------------------------------------------------------------
// Weight pre-pack, TILE-MAJOR for global_load_lds:
//   layout = [k-tile][128 n][32 k] contiguous (4096 u16 = 8192 B per tile).
// enc/c1: hi/lo bf16 pairs; key/sel/val: single bf16.
// ---------------------------------------------------------------------------
__device__ __forceinline__ void packpair(float w, u16* __restrict__ dh,
                                         u16* __restrict__ dl, int i){
  u16 h = f2bf(w);
  dh[i] = h;
  dl[i] = f2bf(w - bf2f(h));
}

__global__ __launch_bounds__(256) void k_pack(
    const float* __restrict__ enc_w, const float* __restrict__ aenc_w,
    const float* __restrict__ key_w, const float* __restrict__ sel_w,
    const float* __restrict__ val_w, const float* __restrict__ c1_w,
    u16* __restrict__ encH, u16* __restrict__ encL,
    u16* __restrict__ aencH, u16* __restrict__ aencL,
    u16* __restrict__ keyH, u16* __restrict__ selH, u16* __restrict__ valH,
    u16* __restrict__ c1H, u16* __restrict__ c1L)
{
  int i = blockIdx.x * 256 + threadIdx.x;
  const int S0 = A_N * H_N * SAF;      // 163840 enc (5 tiles/agent)
  const int S1 = A_N * H_N * OUT_N;    // 32768 aenc
  const int S2 = KD_N * H_N;           // 16384 per key/sel/val (4 tiles)
  const int S5 = A_N * H_N * CIN_N;    // 262144 c1 (8 tiles/agent)
  if (i < S0){
    int a = i / (H_N * SAF); int r = i % (H_N * SAF);
    int tile = r >> 12; int rr = r & 4095;
    int n = rr >> 5; int kk = rr & 31;
    int kg = tile * 32 + kk;
    packpair(enc_w[((size_t)a * SAF + kg) * H_N + n], encH, encL, i);
    return;
  }
  i -= S0;
  if (i < S1){
    int a = i >> 12; int rr = i & 4095;
    int n = rr >> 5; int k = rr & 31;
    packpair(aenc_w[((size_t)a * OUT_N + k) * H_N + n], aencH, aencL, i);
    return;
  }
  i -= S1;
  if (i < 3 * S2){
    int which = i / S2; int j = i % S2;
    int tile = j >> 12; int rr = j & 4095;
    int n = rr >> 5; int kk = rr & 31;
    int kg = tile * 32 + kk;
    const float* w = (which == 0) ? key_w : ((which == 1) ? sel_w : val_w);
    u16* dh = (which == 0) ? keyH : ((which == 1) ? selH : valH);
    dh[j] = f2bf(w[(((size_t)(n >> 5)) * H_N + kg) * D_N + (n & 31)]);
    return;
  }
  i -= 3 * S2;
  if (i < S5){
    int a = i >> 15; int r = i & 32767;
    int tile = r >> 12; int rr = r & 4095;
    int n = rr >> 5; int kk = rr & 31;
    int kg = tile * 32 + kk;
    packpair(c1_w[((size_t)a * CIN_N + kg) * H_N + n], c1H, c1L, i);
  }
}
#define PACK_TOTAL (A_N*H_N*SAF + A_N*H_N*OUT_N + 3*KD_N*H_N + A_N*H_N*CIN_N)

// ---------------------------------------------------------------------------
// Fused kernel 1: sa_enc = lrelu(BN(concat) @ enc_w + enc_b)  [3-term, BK=32,
//   K=160], sels = sa_enc @ sel_w [1-term, BK=64].
// R1-proven synchronous structure, linear tiles, linear frag reads.
// ---------------------------------------------------------------------------
__global__ __launch_bounds__(256, 3) void k_enc_sel(
    const float* __restrict__ states, const float* __restrict__ actions,
    const float* __restrict__ mean, const float* __restrict__ istd,
    const u16* __restrict__ encH, const u16* __restrict__ encL,
    const float* __restrict__ enc_b,
    const u16* __restrict__ selH,
    u16* __restrict__ sa_enc, u16* __restrict__ sels)
{
  int a = blockIdx.y; int row0 = blockIdx.x * 128; int t = threadIdx.x;
  int lane = t & 63, wave = t >> 6, l16 = lane & 15, quad = lane >> 4;
  __shared__ __align__(16) u16 S[25600];
  __shared__ __align__(16) float sc[160], sh[160];
  u16* Wh = S;            // [128][32] enc weight hi tile (phase 1)
  u16* Wl = S + 4096;     // [128][32]
  u16* Xh = S + 8192;     // [128][40]
  u16* Xl = S + 13312;    // [128][40]
  u16* T  = S;            // [128][136] (phase-1 output / phase-2 A)
  u16* Ws = S + 17408;    // [2][128][32] sel weight tiles (phase 2)

  if (t < SAF){
    float m = mean[a * SAF + t], s = istd[a * SAF + t];
    sc[t] = s; sh[t] = -m * s;
  }
  floatx4 acc[2][8];
  #pragma unroll
  for (int mt = 0; mt < 2; ++mt)
    #pragma unroll
    for (int nt = 0; nt < 8; ++nt) acc[mt][nt] = (floatx4){0.f,0.f,0.f,0.f};
  const u16* ebh = encH + (size_t)a * (H_N * SAF);
  const u16* ebl = encL + (size_t)a * (H_N * SAF);
  __syncthreads();

  // ---- phase 1: enc GEMM (3-term split), K=160, BK=32 ----
  for (int k0 = 0; k0 < SAF; k0 += 32){
    const u16* th = ebh + (k0 >> 5) * 4096;
    const u16* tl = ebl + (k0 >> 5) * 4096;
    #pragma unroll
    for (int c = t; c < 512; c += 256){
      glds16(th + c * 8, Wh + c * 8);
      glds16(tl + c * 8, Wl + c * 8);
    }
    for (int c = t; c < 1024; c += 256){
      int r = c >> 3, kc = (c & 7) * 4, f = k0 + kc;
      size_t row = (size_t)a * B_N + row0 + r;
      float4 v;
      if (f < IN_N) v = *(const float4*)(states + row * IN_N + f);
      else          v = *(const float4*)(actions + row * OUT_N + (f - IN_N));
      float4 scv = *(const float4*)&sc[f];
      float4 shv = *(const float4*)&sh[f];
      float x0 = fmaf(v.x, scv.x, shv.x), x1 = fmaf(v.y, scv.y, shv.y);
      float x2 = fmaf(v.z, scv.z, shv.z), x3 = fmaf(v.w, scv.w, shv.w);
      u16 h0 = f2bf(x0), h1 = f2bf(x1), h2 = f2bf(x2), h3 = f2bf(x3);
      uint2 hv; hv.x = (u32)h0 | ((u32)h1 << 16); hv.y = (u32)h2 | ((u32)h3 << 16);
      *(uint2*)&Xh[r * 40 + kc] = hv;
      u16 l0 = f2bf(x0 - bf2f(h0)), l1 = f2bf(x1 - bf2f(h1));
      u16 l2 = f2bf(x2 - bf2f(h2)), l3 = f2bf(x3 - bf2f(h3));
      uint2 lv; lv.x = (u32)l0 | ((u32)l1 << 16); lv.y = (u32)l2 | ((u32)l3 << 16);
      *(uint2*)&Xl[r * 40 + kc] = lv;
    }
    __syncthreads();
    {
      short8 ah[2], al[2], bh[8], bl[8];
      #pragma unroll
      for (int mt = 0; mt < 2; ++mt){
        int rr = (wave * 32 + mt * 16 + l16) * 40 + quad * 8;
        ah[mt] = *(const short8*)&Xh[rr];
        al[mt] = *(const short8*)&Xl[rr];
      }
      #pragma unroll
      for (int nt = 0; nt < 8; ++nt){
        int rr = (nt * 16 + l16) * 32 + quad * 8;
        bh[nt] = *(const short8*)&Wh[rr];
        bl[nt] = *(const short8*)&Wl[rr];
      }
      #pragma unroll
      for (int mt = 0; mt < 2; ++mt)
        #pragma unroll
        for (int nt = 0; nt < 8; ++nt){
          acc[mt][nt] = __builtin_amdgcn_mfma_f32_16x16x32_bf16(ah[mt], bh[nt], acc[mt][nt], 0,0,0);
          acc[mt][nt] = __builtin_amdgcn_mfma_f32_16x16x32_bf16(ah[mt], bl[nt], acc[mt][nt], 0,0,0);
          acc[mt][nt] = __builtin_amdgcn_mfma_f32_16x16x32_bf16(al[mt], bh[nt], acc[mt][nt], 0,0,0);
        }
    }
    __syncthreads();
  }

  // ---- phase-1 epilogue: lrelu+bias -> bf16 tile T in LDS ----
  {
    float bv[8];
    #pragma unroll
    for (int nt = 0; nt < 8; ++nt) bv[nt] = enc_b[a * H_N + nt * 16 + l16];
    #pragma unroll
    for (int mt = 0; mt < 2; ++mt)
      #pragma unroll
      for (int nt = 0; nt < 8; ++nt)
        #pragma unroll
        for (int r = 0; r < 4; ++r){
          int rl = wave * 32 + mt * 16 + quad * 4 + r;
          T[rl * 136 + nt * 16 + l16] = f2bf(lrelu(acc[mt][nt][r] + bv[nt]));
        }
  }
  __syncthreads();
  // vectorized sa_enc store from tile
  for (int c = t; c < 2048; c += 256){
    int row = c >> 4, col8 = (c & 15) * 8;
    *(uint4*)(sa_enc + ((size_t)a * B_N + row0 + row) * H_N + col8) =
        *(const uint4*)&T[row * 136 + col8];
  }

  // ---- phase 2: sels = T @ selT (single-term), BK=64 ----
  #pragma unroll
  for (int mt = 0; mt < 2; ++mt)
    #pragma unroll
    for (int nt = 0; nt < 8; ++nt) acc[mt][nt] = (floatx4){0.f,0.f,0.f,0.f};
  for (int k0 = 0; k0 < H_N; k0 += 64){
    #pragma unroll
    for (int c = t; c < 1024; c += 256)
      glds16(selH + (k0 >> 5) * 4096 + c * 8, Ws + c * 8);
    __syncthreads();
    #pragma unroll
    for (int ks = 0; ks < 64; ks += 32){
      short8 ah[2], bh[8];
      #pragma unroll
      for (int mt = 0; mt < 2; ++mt)
        ah[mt] = *(const short8*)&T[(wave * 32 + mt * 16 + l16) * 136 + k0 + ks + quad * 8];
      #pragma unroll
      for (int nt = 0; nt < 8; ++nt)
        bh[nt] = *(const short8*)&Ws[((ks >> 5) << 12) + (nt * 16 + l16) * 32 + quad * 8];
      #pragma unroll
      for (int mt = 0; mt < 2; ++mt)
        #pragma unroll
        for (int nt = 0; nt < 8; ++nt)
          acc[mt][nt] = __builtin_amdgcn_mfma_f32_16x16x32_bf16(ah[mt], bh[nt], acc[mt][nt], 0,0,0);
    }
    __syncthreads();
  }
  #pragma unroll
  for (int mt = 0; mt < 2; ++mt)
    #pragma unroll
    for (int nt = 0; nt < 8; ++nt)
      #pragma unroll
      for (int r = 0; r < 4; ++r){
        int rl = wave * 32 + mt * 16 + quad * 4 + r;
        T[rl * 136 + nt * 16 + l16] = f2bf(acc[mt][nt][r]);
      }
  __syncthreads();
  for (int c = t; c < 2048; c += 256){
    int row = c >> 4, col8 = (c & 15) * 8;
    *(uint4*)(sels + ((size_t)a * B_N + row0 + row) * H_N + col8) =
        *(const uint4*)&T[row * 136 + col8];
  }
}

// ---------------------------------------------------------------------------
// Fused kernel 2: a_enc = lrelu(BN(actions) @ aenc_w + aenc_b) [3-term, K=32]
//   keys & vals in ONE dual-accumulator loop, BK=32 staging.
// LDS shrunk 69.6 -> 51.2 KB (single W tiles + dual-pass epilogue through
// one T tile) -> 3 blocks/CU (was 2): +50% waves for latency hiding.
// ---------------------------------------------------------------------------
__global__ __launch_bounds__(256, 3) void k_aenc_kv(
    const float* __restrict__ actions,
    const float* __restrict__ mean, const float* __restrict__ istd,
    const u16* __restrict__ aencH, const u16* __restrict__ aencL,
    const float* __restrict__ aenc_b,
    const u16* __restrict__ keyH, const u16* __restrict__ valH,
    const float* __restrict__ val_b,
    u16* __restrict__ keys, u16* __restrict__ vals)
{
  int a = blockIdx.y; int row0 = blockIdx.x * 128; int t = threadIdx.x;
  int lane = t & 63, wave = t >> 6, l16 = lane & 15, quad = lane >> 4;
  __shared__ __align__(16) u16 S[25600];
  __shared__ __align__(16) float sc[32], sh[32];
  u16* T  = S;            // [128][136] a_enc tile; epilogue vals/keys tile
  u16* WK = S + 17408;    // [128][32] key weight tile (BK=32)
  u16* WV = S + 21504;    // [128][32] val weight tile

  if (t < 32){
    float m = mean[a * SAF + 128 + t], s = istd[a * SAF + 128 + t];
    sc[t] = s; sh[t] = -m * s;
  }
  floatx4 accK[2][8], accV[2][8];
  #pragma unroll
  for (int mt = 0; mt < 2; ++mt)
    #pragma unroll
    for (int nt = 0; nt < 8; ++nt){
      accK[mt][nt] = (floatx4){0.f,0.f,0.f,0.f};
      accV[mt][nt] = (floatx4){0.f,0.f,0.f,0.f};
    }
  __syncthreads();

  // ---- phase 1: aenc GEMM, K=32 single tile ----
  {
    u16* Wh1 = S;  u16* Wl1 = S + 4096;
    u16* Xh = S + 8192; u16* Xl = S + 13312;  // [128][40], ends 18432
    const u16* abh = aencH + (size_t)a * 4096;
    const u16* abl = aencL + (size_t)a * 4096;
    #pragma unroll
    for (int c = t; c < 512; c += 256){
      glds16(abh + c * 8, Wh1 + c * 8);
      glds16(abl + c * 8, Wl1 + c * 8);
    }
    for (int c = t; c < 1024; c += 256){
      int r = c >> 3, kc = (c & 7) * 4;
      size_t row = (size_t)a * B_N + row0 + r;
      float4 v = *(const float4*)(actions + row * OUT_N + kc);
      float4 scv = *(const float4*)&sc[kc];
      float4 shv = *(const float4*)&sh[kc];
      float x0 = fmaf(v.x, scv.x, shv.x), x1 = fmaf(v.y, scv.y, shv.y);
      float x2 = fmaf(v.z, scv.z, shv.z), x3 = fmaf(v.w, scv.w, shv.w);
      u16 h0 = f2bf(x0), h1 = f2bf(x1), h2 = f2bf(x2), h3 = f2bf(x3);
      uint2 hv; hv.x = (u32)h0 | ((u32)h1 << 16); hv.y = (u32)h2 | ((u32)h3 << 16);
      *(uint2*)&Xh[r * 40 + kc] = hv;
      u16 l0 = f2bf(x0 - bf2f(h0)), l1 = f2bf(x1 - bf2f(h1));
      u16 l2 = f2bf(x2 - bf2f(h2)), l3 = f2bf(x3 - bf2f(h3));
      uint2 lv; lv.x = (u32)l0 | ((u32)l1 << 16); lv.y = (u32)l2 | ((u32)l3 << 16);
      *(uint2*)&Xl[r * 40 + kc] = lv;
    }
    __syncthreads();
    short8 ah[2], al[2], bh[8], bl[8];
    #pragma unroll
    for (int mt = 0; mt < 2; ++mt){
      int rr = (wave * 32 + mt * 16 + l16) * 40 + quad * 8;
      ah[mt] = *(const short8*)&Xh[rr];
      al[mt] = *(const short8*)&Xl[rr];
    }
    #pragma unroll
    for (int nt = 0; nt < 8; ++nt){
      int rr = (nt * 16 + l16) * 32 + quad * 8;
      bh[nt] = *(const short8*)&Wh1[rr];
      bl[nt] = *(const short8*)&Wl1[rr];
    }
    #pragma unroll
    for (int mt = 0; mt < 2; ++mt)
      #pragma unroll
      for (int nt = 0; nt < 8; ++nt){
        accK[mt][nt] = __builtin_amdgcn_mfma_f32_16x16x32_bf16(ah[mt], bh[nt], accK[mt][nt], 0,0,0);
        accK[mt][nt] = __builtin_amdgcn_mfma_f32_16x16x32_bf16(ah[mt], bl[nt], accK[mt][nt], 0,0,0);
        accK[mt][nt] = __builtin_amdgcn_mfma_f32_16x16x32_bf16(al[mt], bh[nt], accK[mt][nt], 0,0,0);
      }
    __syncthreads();
  }
  // a_enc -> LDS tile T; move from accK, then zero accK
  {
    float bv[8];
    #pragma unroll
    for (int nt = 0; nt < 8; ++nt) bv[nt] = aenc_b[a * H_N + nt * 16 + l16];
    #pragma unroll
    for (int mt = 0; mt < 2; ++mt)
      #pragma unroll
      for (int nt = 0; nt < 8; ++nt){
        #pragma unroll
        for (int r = 0; r < 4; ++r){
          int rl = wave * 32 + mt * 16 + quad * 4 + r;
          T[rl * 136 + nt * 16 + l16] = f2bf(lrelu(accK[mt][nt][r] + bv[nt]));
        }
        accK[mt][nt] = (floatx4){0.f,0.f,0.f,0.f};
      }
  }

  // ---- phase 2: keys + vals in one dual-acc loop (BK=32, single-term) ----
  for (int k0 = 0; k0 < H_N; k0 += 32){
    __syncthreads();
    #pragma unroll
    for (int c = t; c < 512; c += 256){
      glds16(keyH + (k0 >> 5) * 4096 + c * 8, WK + c * 8);
      glds16(valH + (k0 >> 5) * 4096 + c * 8, WV + c * 8);
    }
    __syncthreads();
    {
      short8 ah[2], bk[8], bv[8];
      #pragma unroll
      for (int mt = 0; mt < 2; ++mt)
        ah[mt] = *(const short8*)&T[(wave * 32 + mt * 16 + l16) * 136 + k0 + quad * 8];
      #pragma unroll
      for (int nt = 0; nt < 8; ++nt){
        int rr = (nt * 16 + l16) * 32 + quad * 8;
        bk[nt] = *(const short8*)&WK[rr];
        bv[nt] = *(const short8*)&WV[rr];
      }
      #pragma unroll
      for (int mt = 0; mt < 2; ++mt)
        #pragma unroll
        for (int nt = 0; nt < 8; ++nt){
          accK[mt][nt] = __builtin_amdgcn_mfma_f32_16x16x32_bf16(ah[mt], bk[nt], accK[mt][nt], 0,0,0);
          accV[mt][nt] = __builtin_amdgcn_mfma_f32_16x16x32_bf16(ah[mt], bv[nt], accV[mt][nt], 0,0,0);
        }
    }
  }
  __syncthreads();
  // epilogue pass 1: vals (bias+lrelu) through T
  {
    float bv[8];
    #pragma unroll
    for (int nt = 0; nt < 8; ++nt) bv[nt] = val_b[nt * 16 + l16];
    #pragma unroll
    for (int mt = 0; mt < 2; ++mt)
      #pragma unroll
      for (int nt = 0; nt < 8; ++nt)
        #pragma unroll
        for (int r = 0; r < 4; ++r){
          int rl = wave * 32 + mt * 16 + quad * 4 + r;
          T[rl * 136 + nt * 16 + l16] = f2bf(lrelu(accV[mt][nt][r] + bv[nt]));
        }
  }
  __syncthreads();
  for (int c = t; c < 2048; c += 256){
    int row = c >> 4, col8 = (c & 15) * 8;
    *(uint4*)(vals + ((size_t)a * B_N + row0 + row) * H_N + col8) =
        *(const uint4*)&T[row * 136 + col8];
  }
  __syncthreads();
  // epilogue pass 2: keys through T
  #pragma unroll
  for (int mt = 0; mt < 2; ++mt)
    #pragma unroll
    for (int nt = 0; nt < 8; ++nt)
      #pragma unroll
      for (int r = 0; r < 4; ++r){
        int rl = wave * 32 + mt * 16 + quad * 4 + r;
        T[rl * 136 + nt * 16 + l16] = f2bf(accK[mt][nt][r]);
      }
  __syncthreads();
  for (int c = t; c < 2048; c += 256){
    int row = c >> 4, col8 = (c & 15) * 8;
    *(uint4*)(keys + ((size_t)a * B_N + row0 + row) * H_N + col8) =
        *(const uint4*)&T[row * 136 + col8];
  }
}

// ---------------------------------------------------------------------------
// Attention. LDS tiles permuted at 16B-unit granularity:
//   U(aa,bl,kk,dg) = (bl*4+dg)*32 + kk*8 + (aa ^ (kk<<1) ^ dg)
// Old row-major layout made the si gather a 32-way bank conflict. Permuted:
// staging writes and K/V dot reads 2-way (free). Same 24 KB. `other` may
// alias `keys` (reads complete before __syncthreads; rows disjoint).
// ---------------------------------------------------------------------------
__global__ __launch_bounds__(256) void k_attn(
    const u16* __restrict__ sels, const u16* __restrict__ keys,
    const u16* __restrict__ vals, u16* __restrict__ other)
{
  int b0 = blockIdx.x * 8;
  int t = threadIdx.x;
  __shared__ __align__(16) u16 sS[8192], sK[8192], sV[8192];
  #pragma unroll
  for (int c = t; c < 1024; c += 256){
    int pr = c >> 4, uir = c & 15;
    int aa = pr & 7, bl2 = pr >> 3;
    int kk = uir >> 2, dg = uir & 3;
    int U = (bl2 * 4 + dg) * 32 + kk * 8 + (aa ^ (kk << 1) ^ dg);
    size_t go = ((size_t)aa * B_N + b0 + bl2) * KD_N;
    ((uint4*)sS)[U] = *((const uint4*)(sels + go) + uir);
    ((uint4*)sK)[U] = *((const uint4*)(keys + go) + uir);
    ((uint4*)sV)[U] = *((const uint4*)(vals + go) + uir);
  }
  __syncthreads();
  int i = t & 7, k = (t >> 3) & 3, bl = t >> 5;
  float si[32];
  #pragma unroll
  for (int dg = 0; dg < 4; ++dg){
    int U = (bl * 4 + dg) * 32 + k * 8 + (i ^ (k << 1) ^ dg);
    uint4 s4 = ((const uint4*)sS)[U];
    const u32* sp = (const u32*)&s4;
    #pragma unroll
    for (int jj = 0; jj < 4; ++jj){
      int d2 = dg * 4 + jj;
      si[2 * d2] = bf_lo(sp[jj]); si[2 * d2 + 1] = bf_hi(sp[jj]);
    }
  }
  float lg[8];
  #pragma unroll
  for (int j = 0; j < 8; ++j){
    float acc = 0.f;
    #pragma unroll
    for (int dg = 0; dg < 4; ++dg){
      int U = (bl * 4 + dg) * 32 + k * 8 + (j ^ (k << 1) ^ dg);
      uint4 k4 = ((const uint4*)sK)[U];
      const u32* kp = (const u32*)&k4;
      #pragma unroll
      for (int jj = 0; jj < 4; ++jj){
        int d2 = dg * 4 + jj;
        acc = fmaf(si[2 * d2], bf_lo(kp[jj]), acc);
        acc = fmaf(si[2 * d2 + 1], bf_hi(kp[jj]), acc);
      }
    }
    lg[j] = acc * 0.17677669529663689f;
  }
  float mx = -3.0e38f;
  #pragma unroll
  for (int j = 0; j < 8; ++j) if (j != i) mx = fmaxf(mx, lg[j]);
  float pe[8], se = 0.f;
  #pragma unroll
  for (int j = 0; j < 8; ++j){
    pe[j] = (j == i) ? 0.f : __expf(lg[j] - mx);
    se += pe[j];
  }
  float inv = 1.f / se;
  #pragma unroll
  for (int j = 0; j < 8; ++j) pe[j] *= inv;
  float o0[16], o1[16];
  #pragma unroll
  for (int d2 = 0; d2 < 16; ++d2){ o0[d2] = 0.f; o1[d2] = 0.f; }
  #pragma unroll
  for (int j = 0; j < 8; ++j){
    #pragma unroll
    for (int dg = 0; dg < 4; ++dg){
      int U = (bl * 4 + dg) * 32 + k * 8 + (j ^ (k << 1) ^ dg);
      uint4 v4 = ((const uint4*)sV)[U];
      const u32* vp = (const u32*)&v4;
      #pragma unroll
      for (int jj = 0; jj < 4; ++jj){
        int d2 = dg * 4 + jj;
        o0[d2] = fmaf(pe[j], bf_lo(vp[jj]), o0[d2]);
        o1[d2] = fmaf(pe[j], bf_hi(vp[jj]), o1[d2]);
      }
    }
  }
  __align__(16) u16 ob[32];
  #pragma unroll
  for (int d2 = 0; d2 < 16; ++d2){
    ob[2 * d2] = f2bf(o0[d2]); ob[2 * d2 + 1] = f2bf(o1[d2]);
  }
  uint4* dst = (uint4*)(other + ((size_t)i * B_N + (b0 + bl)) * KD_N + k * 32);
  const uint4* s4o = (const uint4*)ob;
  #pragma unroll
  for (int c = 0; c < 4; ++c) dst[c] = s4o[c];
}

// ---------------------------------------------------------------------------
// Critic: h = lrelu([sa_enc|other] @ c1_w + c1_b); q = h . c2_w + c2_b
// M=256 rows per block, 512 threads (8 waves): halves per-row weight staging
// and barrier count; LDS only 32 KB -> ~24 waves/CU (was 12). Per-wave frag
// tiling unchanged (2x8), so VGPR stays ~84.
// ---------------------------------------------------------------------------
__global__ __launch_bounds__(512, 4) void k_critic(
    const u16* __restrict__ sa_enc, const u16* __restrict__ other,
    const u16* __restrict__ c1H, const u16* __restrict__ c1L,
    const float* __restrict__ c1_b,
    const float* __restrict__ c2w, const float* __restrict__ c2b,
    float* __restrict__ qout)
{
  int a = blockIdx.y; int row0 = blockIdx.x * 256; int t = threadIdx.x;
  int lane = t & 63, wave = t >> 6, l16 = lane & 15, quad = lane >> 4;
  __shared__ __align__(16) u16 Xs[8192];   // [256][32]
  __shared__ __align__(16) u16 Wh[4096];   // [128][32]
  __shared__ __align__(16) u16 Wl[4096];
  floatx4 acc[2][8];
  #pragma unroll
  for (int mt = 0; mt < 2; ++mt)
    #pragma unroll
    for (int nt = 0; nt < 8; ++nt) acc[mt][nt] = (floatx4){0.f,0.f,0.f,0.f};
  const u16* wbh = c1H + (size_t)a * (H_N * CIN_N);
  const u16* wbl = c1L + (size_t)a * (H_N * CIN_N);

  for (int kt = 0; kt < 8; ++kt){
    const u16* th = wbh + kt * 4096;
    const u16* tl = wbl + kt * 4096;
    {
      int c = t;
      if (c < 512){
        glds16(th + c * 8, Wh + c * 8);
        glds16(tl + c * 8, Wl + c * 8);
      }
    }
    {
      const u16* src = (kt < 4) ? sa_enc : other;
      int kb = (kt < 4) ? kt * 32 : kt * 32 - H_N;
      #pragma unroll
      for (int c = t; c < 1024; c += 512){
        int r = c >> 2, off = (c & 3) * 8;
        glds16(src + ((size_t)a * B_N + row0 + r) * H_N + kb + off, Xs + c * 8);
      }
    }
    __syncthreads();
    {
      short8 ah[2], bh[8], bl[8];
      #pragma unroll
      for (int mt = 0; mt < 2; ++mt)
        ah[mt] = *(const short8*)&Xs[(wave * 32 + mt * 16 + l16) * 32 + quad * 8];
      #pragma unroll
      for (int nt = 0; nt < 8; ++nt){
        int rr = (nt * 16 + l16) * 32 + quad * 8;
        bh[nt] = *(const short8*)&Wh[rr];
        bl[nt] = *(const short8*)&Wl[rr];
      }
      #pragma unroll
      for (int mt = 0; mt < 2; ++mt)
        #pragma unroll
        for (int nt = 0; nt < 8; ++nt){
          acc[mt][nt] = __builtin_amdgcn_mfma_f32_16x16x32_bf16(ah[mt], bh[nt], acc[mt][nt], 0,0,0);
          acc[mt][nt] = __builtin_amdgcn_mfma_f32_16x16x32_bf16(ah[mt], bl[nt], acc[mt][nt], 0,0,0);
        }
    }
    __syncthreads();
  }

  float c2r[8], bv[8];
  #pragma unroll
  for (int nt = 0; nt < 8; ++nt){
    c2r[nt] = c2w[a * H_N + nt * 16 + l16];
    bv[nt]  = c1_b[a * H_N + nt * 16 + l16];
  }
  #pragma unroll
  for (int mt = 0; mt < 2; ++mt){
    #pragma unroll
    for (int r = 0; r < 4; ++r){
      float s = 0.f;
      #pragma unroll
      for (int nt = 0; nt < 8; ++nt){
        float h = lrelu(acc[mt][nt][r] + bv[nt]);
        s = fmaf(h, c2r[nt], s);
      }
      s += __shfl_xor(s, 1);
      s += __shfl_xor(s, 2);
      s += __shfl_xor(s, 4);
      s += __shfl_xor(s, 8);
      if (l16 == 0){
        int row = row0 + wave * 32 + mt * 16 + quad * 4 + r;
        qout[(size_t)a * B_N + row] = s + c2b[a];
      }
    }
  }
}

// ---------------------------------------------------------------------------
extern "C" void kernel_launch(void* const* d_in, const int* in_sizes, int n_in,
                              void* d_out, int out_size, void* d_ws, size_t ws_size,
                              hipStream_t stream)
{
  const float* states  = (const float*)d_in[0];
  const float* actions = (const float*)d_in[1];
  const float* enc_w   = (const float*)d_in[2];
  const float* enc_b   = (const float*)d_in[3];
  const float* aenc_w  = (const float*)d_in[4];
  const float* aenc_b  = (const float*)d_in[5];
  const float* key_w   = (const float*)d_in[6];
  const float* sel_w   = (const float*)d_in[7];
  const float* val_w   = (const float*)d_in[8];
  const float* val_b   = (const float*)d_in[9];
  const float* c1_w    = (const float*)d_in[10];
  const float* c1_b    = (const float*)d_in[11];
  const float* c2_w    = (const float*)d_in[12];
  const float* c2_b    = (const float*)d_in[13];
  float* q = (float*)d_out;

  char* ws = (char*)d_ws;
  // Pack region [0, 884,736) overlaps stats partials [0, 1,310,720):
  // stats/finalize consume `part` before k_pack overwrites (sequential stream).
  u16* encH  = (u16*)(ws + 0);          // 327680 B
  u16* encL  = (u16*)(ws + 327680);     // 327680 B
  u16* aencH = (u16*)(ws + 655360);     //  65536 B
  u16* aencL = (u16*)(ws + 720896);     //  65536 B
  u16* keyH  = (u16*)(ws + 786432);     //  32768 B
  u16* selH  = (u16*)(ws + 819200);     //  32768 B
  u16* valH  = (u16*)(ws + 851968);     //  32768 B -> ends 884,736
  float* part    = (float*)ws;          // 1,310,720 B (dead after finalize)
  float* meanArr = (float*)(ws + 1310720);
  float* istdArr = (float*)(ws + 1315840);
  u16* c1H = (u16*)(ws + 1320960);      // 524288 B
  u16* c1L = (u16*)(ws + 1845248);      // 524288 B -> ends 2,369,536
  const size_t ibase = 4194304;
  const size_t BUF = (size_t)A_N * B_N * 128 * 2;   // 64 MB
  u16* sa_enc = (u16*)(ws + ibase);
  u16* sels   = (u16*)(ws + ibase + BUF);
  u16* keys   = (u16*)(ws + ibase + 2 * BUF);       // keys, later `other`
  u16* vals   = (u16*)(ws + ibase + 3 * BUF);

  k_stats<<<dim3(CHUNKS, A_N), 256, 0, stream>>>(states, actions, part);
  k_finalize<<<(A_N * SAF + 255) / 256, 256, 0, stream>>>(part, meanArr, istdArr);
  k_pack<<<(PACK_TOTAL + 255) / 256, 256, 0, stream>>>(
      enc_w, aenc_w, key_w, sel_w, val_w, c1_w,
      encH, encL, aencH, aencL, keyH, selH, valH, c1H, c1L);

  dim3 g(B_N / 128, A_N);
  k_enc_sel<<<g, 256, 0, stream>>>(states, actions, meanArr, istdArr,
                                   encH, encL, enc_b, selH, sa_enc, sels);
  k_aenc_kv<<<g, 256, 0, stream>>>(actions, meanArr, istdArr,
                                   aencH, aencL, aenc_b, keyH, valH, val_b,
                                   keys, vals);
  k_attn<<<B_N / 8, 256, 0, stream>>>(sels, keys, vals, keys);  // other -> keys
  dim3 gc(B_N / 256, A_N);
  k_critic<<<gc, 512, 0, stream>>>(sa_enc, keys, c1H, c1L, c1_b, c2_w, c2_b, q);
}

// Round 6
// 511.039 us; speedup vs baseline: 1.3045x; 1.3045x over previous
//
#include <hip/hip_runtime.h>
#include <hip/hip_bf16.h>
#include <stdint.h>

// Problem constants
#define A_N 8
#define B_N 32768
#define IN_N 128
#define OUT_N 32
#define SAF 160      // IN + OUT  (= enc K, exactly 5 x 32: NO pad)
#define H_N 128
#define D_N 32
#define KD_N 128     // K*D
#define CIN_N 256    // critic input = H + K*D
#define CHUNKS 128   // stats chunks over B
#define EPSV 1e-5f

typedef unsigned int u32;
typedef unsigned short u16;
typedef __attribute__((ext_vector_type(8))) short short8;    // 8 bf16 (4 VGPRs)
typedef __attribute__((ext_vector_type(4))) float floatx4;   // MFMA C/D

// async global->LDS, 16B per lane. LDS dest = wave-uniform base + lane*16,
// so dest layout MUST be linear in lane order; source kept linear too
// (R3: permuted sources defeat VMEM coalescing). Weight tiles are packed
// tile-major [k-tile][128 n][32 k] so linear glds lands correctly.
// R2-R4 lesson: LDS XOR-swizzle cut SQ_LDS_BANK_CONFLICT 6.4M->2.75M but
// XOR-compensated frag reads cost +21us pure stall -- conflicts were never
// on the critical path. Linear everywhere.
// R5 lesson: before __launch_bounds__ changes, compute AGPR+VGPR floor vs
// budget: critic needs ~148 regs -> 512-thread blocks infeasible (spilled).
typedef __attribute__((address_space(1))) void gvoid;
typedef __attribute__((address_space(3))) void lvoid;
__device__ __forceinline__ void glds16(const void* g, void* l){
  __builtin_amdgcn_global_load_lds((gvoid*)g, (lvoid*)l, 16, 0, 0);
}

__device__ __forceinline__ float bf_lo(u32 u){ return __uint_as_float(u << 16); }
__device__ __forceinline__ float bf_hi(u32 u){ return __uint_as_float(u & 0xffff0000u); }
__device__ __forceinline__ float bf2f(u16 b){ return __uint_as_float(((u32)b) << 16); }
__device__ __forceinline__ u16 f2bf(float f){
  u32 u = __float_as_uint(f);
  return (u16)((u + 0x7fffu + ((u >> 16) & 1u)) >> 16);
}
__device__ __forceinline__ float lrelu(float x){ return x > 0.f ? x : 0.01f * x; }

// ---------------------------------------------------------------------------
// Stage 1: BN statistics (sum, sumsq) per (agent, feature).
// states loop vectorized to float4 (128 MB stream, was scalar 4B/lane).
// ---------------------------------------------------------------------------
__global__ __launch_bounds__(256) void k_stats(
    const float* __restrict__ states, const float* __restrict__ actions,
    float* __restrict__ part)
{
  int a = blockIdx.y;
  int chunk = blockIdx.x;
  int t = threadIdx.x;
  int r0 = chunk * (B_N / CHUNKS);   // 256 rows per chunk
  __shared__ __align__(16) float red[2048];
  {
    // thread: features f4*4..+3, rows g, g+8, ... (32 iters)
    int f4 = t & 31, g = t >> 5;
    const float4* p = (const float4*)(states + ((size_t)a * B_N + r0 + g) * IN_N) + f4;
    float4 s1 = {0.f,0.f,0.f,0.f}, s2 = {0.f,0.f,0.f,0.f};
    for (int it = 0; it < 32; ++it){
      float4 v = p[(size_t)(8 * it) * (IN_N / 4)];
      s1.x += v.x; s1.y += v.y; s1.z += v.z; s1.w += v.w;
      s2.x = fmaf(v.x, v.x, s2.x); s2.y = fmaf(v.y, v.y, s2.y);
      s2.z = fmaf(v.z, v.z, s2.z); s2.w = fmaf(v.w, v.w, s2.w);
    }
    ((float4*)red)[t] = s1;
    ((float4*)red)[256 + t] = s2;
    __syncthreads();
    if (t < 128){
      int ff4 = t >> 2, j = t & 3;
      float a1 = 0.f, a2 = 0.f;
      #pragma unroll
      for (int gg = 0; gg < 8; ++gg){
        a1 += red[(ff4 + 32 * gg) * 4 + j];
        a2 += red[(256 + ff4 + 32 * gg) * 4 + j];
      }
      size_t o = (((size_t)a * CHUNKS + chunk) * SAF + t) * 2;
      part[o] = a1; part[o + 1] = a2;
    }
    __syncthreads();
  }
  {
    int f = t & 31, g = t >> 5;
    const float* p = actions + ((size_t)a * B_N + r0 + g) * OUT_N + f;
    float s1 = 0.f, s2 = 0.f;
    for (int it = 0; it < 32; ++it){
      float v = p[(size_t)(8 * it) * OUT_N];
      s1 += v; s2 += v * v;
    }
    red[t] = s1; red[256 + t] = s2;
    __syncthreads();
    if (t < 32){
      float a1 = 0.f, a2 = 0.f;
      #pragma unroll
      for (int gg = 0; gg < 8; ++gg){
        a1 += red[t + 32 * gg];
        a2 += red[256 + t + 32 * gg];
      }
      size_t o = (((size_t)a * CHUNKS + chunk) * SAF + 128 + t) * 2;
      part[o] = a1; part[o + 1] = a2;
    }
  }
}

__global__ void k_finalize(const float* __restrict__ part,
                           float* __restrict__ meanArr, float* __restrict__ istdArr)
{
  int idx = blockIdx.x * blockDim.x + threadIdx.x;
  if (idx >= A_N * SAF) return;
  int a = idx / SAF, f = idx % SAF;
  float s1 = 0.f, s2 = 0.f;
  for (int c = 0; c < CHUNKS; ++c){
    size_t o = (((size_t)a * CHUNKS + c) * SAF + f) * 2;
    s1 += part[o]; s2 += part[o + 1];
  }
  float m = s1 * (1.f / B_N);
  float v = s2 * (1.f / B_N) - m * m;
  if (v < 0.f) v = 0.f;
  meanArr[idx] = m;
  istdArr[idx] = rsqrtf(v + EPSV);
}

// ---------------------------------------------------------------------------
// Weight pre-pack, TILE-MAJOR for global_load_lds:
//   layout = [k-tile][128 n][32 k] contiguous (4096 u16 = 8192 B per tile).
// enc/c1: hi/lo bf16 pairs; key/sel/val: single bf16.
// ---------------------------------------------------------------------------
__device__ __forceinline__ void packpair(float w, u16* __restrict__ dh,
                                         u16* __restrict__ dl, int i){
  u16 h = f2bf(w);
  dh[i] = h;
  dl[i] = f2bf(w - bf2f(h));
}

__global__ __launch_bounds__(256) void k_pack(
    const float* __restrict__ enc_w, const float* __restrict__ aenc_w,
    const float* __restrict__ key_w, const float* __restrict__ sel_w,
    const float* __restrict__ val_w, const float* __restrict__ c1_w,
    u16* __restrict__ encH, u16* __restrict__ encL,
    u16* __restrict__ aencH, u16* __restrict__ aencL,
    u16* __restrict__ keyH, u16* __restrict__ selH, u16* __restrict__ valH,
    u16* __restrict__ c1H, u16* __restrict__ c1L)
{
  int i = blockIdx.x * 256 + threadIdx.x;
  const int S0 = A_N * H_N * SAF;      // 163840 enc (5 tiles/agent)
  const int S1 = A_N * H_N * OUT_N;    // 32768 aenc
  const int S2 = KD_N * H_N;           // 16384 per key/sel/val (4 tiles)
  const int S5 = A_N * H_N * CIN_N;    // 262144 c1 (8 tiles/agent)
  if (i < S0){
    int a = i / (H_N * SAF); int r = i % (H_N * SAF);
    int tile = r >> 12; int rr = r & 4095;
    int n = rr >> 5; int kk = rr & 31;
    int kg = tile * 32 + kk;
    packpair(enc_w[((size_t)a * SAF + kg) * H_N + n], encH, encL, i);
    return;
  }
  i -= S0;
  if (i < S1){
    int a = i >> 12; int rr = i & 4095;
    int n = rr >> 5; int k = rr & 31;
    packpair(aenc_w[((size_t)a * OUT_N + k) * H_N + n], aencH, aencL, i);
    return;
  }
  i -= S1;
  if (i < 3 * S2){
    int which = i / S2; int j = i % S2;
    int tile = j >> 12; int rr = j & 4095;
    int n = rr >> 5; int kk = rr & 31;
    int kg = tile * 32 + kk;
    const float* w = (which == 0) ? key_w : ((which == 1) ? sel_w : val_w);
    u16* dh = (which == 0) ? keyH : ((which == 1) ? selH : valH);
    dh[j] = f2bf(w[(((size_t)(n >> 5)) * H_N + kg) * D_N + (n & 31)]);
    return;
  }
  i -= 3 * S2;
  if (i < S5){
    int a = i >> 15; int r = i & 32767;
    int tile = r >> 12; int rr = r & 4095;
    int n = rr >> 5; int kk = rr & 31;
    int kg = tile * 32 + kk;
    packpair(c1_w[((size_t)a * CIN_N + kg) * H_N + n], c1H, c1L, i);
  }
}
#define PACK_TOTAL (A_N*H_N*SAF + A_N*H_N*OUT_N + 3*KD_N*H_N + A_N*H_N*CIN_N)

// ---------------------------------------------------------------------------
// Fused kernel 1: sa_enc = lrelu(BN(concat) @ enc_w + enc_b)  [3-term, BK=32,
//   K=160], sels = sa_enc @ sel_w [1-term, BK=64].
// R1-proven synchronous structure, linear tiles, linear frag reads.
// ---------------------------------------------------------------------------
__global__ __launch_bounds__(256, 3) void k_enc_sel(
    const float* __restrict__ states, const float* __restrict__ actions,
    const float* __restrict__ mean, const float* __restrict__ istd,
    const u16* __restrict__ encH, const u16* __restrict__ encL,
    const float* __restrict__ enc_b,
    const u16* __restrict__ selH,
    u16* __restrict__ sa_enc, u16* __restrict__ sels)
{
  int a = blockIdx.y; int row0 = blockIdx.x * 128; int t = threadIdx.x;
  int lane = t & 63, wave = t >> 6, l16 = lane & 15, quad = lane >> 4;
  __shared__ __align__(16) u16 S[25600];
  __shared__ __align__(16) float sc[160], sh[160];
  u16* Wh = S;            // [128][32] enc weight hi tile (phase 1)
  u16* Wl = S + 4096;     // [128][32]
  u16* Xh = S + 8192;     // [128][40]
  u16* Xl = S + 13312;    // [128][40]
  u16* T  = S;            // [128][136] (phase-1 output / phase-2 A)
  u16* Ws = S + 17408;    // [2][128][32] sel weight tiles (phase 2)

  if (t < SAF){
    float m = mean[a * SAF + t], s = istd[a * SAF + t];
    sc[t] = s; sh[t] = -m * s;
  }
  floatx4 acc[2][8];
  #pragma unroll
  for (int mt = 0; mt < 2; ++mt)
    #pragma unroll
    for (int nt = 0; nt < 8; ++nt) acc[mt][nt] = (floatx4){0.f,0.f,0.f,0.f};
  const u16* ebh = encH + (size_t)a * (H_N * SAF);
  const u16* ebl = encL + (size_t)a * (H_N * SAF);
  __syncthreads();

  // ---- phase 1: enc GEMM (3-term split), K=160, BK=32 ----
  for (int k0 = 0; k0 < SAF; k0 += 32){
    const u16* th = ebh + (k0 >> 5) * 4096;
    const u16* tl = ebl + (k0 >> 5) * 4096;
    #pragma unroll
    for (int c = t; c < 512; c += 256){
      glds16(th + c * 8, Wh + c * 8);
      glds16(tl + c * 8, Wl + c * 8);
    }
    for (int c = t; c < 1024; c += 256){
      int r = c >> 3, kc = (c & 7) * 4, f = k0 + kc;
      size_t row = (size_t)a * B_N + row0 + r;
      float4 v;
      if (f < IN_N) v = *(const float4*)(states + row * IN_N + f);
      else          v = *(const float4*)(actions + row * OUT_N + (f - IN_N));
      float4 scv = *(const float4*)&sc[f];
      float4 shv = *(const float4*)&sh[f];
      float x0 = fmaf(v.x, scv.x, shv.x), x1 = fmaf(v.y, scv.y, shv.y);
      float x2 = fmaf(v.z, scv.z, shv.z), x3 = fmaf(v.w, scv.w, shv.w);
      u16 h0 = f2bf(x0), h1 = f2bf(x1), h2 = f2bf(x2), h3 = f2bf(x3);
      uint2 hv; hv.x = (u32)h0 | ((u32)h1 << 16); hv.y = (u32)h2 | ((u32)h3 << 16);
      *(uint2*)&Xh[r * 40 + kc] = hv;
      u16 l0 = f2bf(x0 - bf2f(h0)), l1 = f2bf(x1 - bf2f(h1));
      u16 l2 = f2bf(x2 - bf2f(h2)), l3 = f2bf(x3 - bf2f(h3));
      uint2 lv; lv.x = (u32)l0 | ((u32)l1 << 16); lv.y = (u32)l2 | ((u32)l3 << 16);
      *(uint2*)&Xl[r * 40 + kc] = lv;
    }
    __syncthreads();
    {
      short8 ah[2], al[2], bh[8], bl[8];
      #pragma unroll
      for (int mt = 0; mt < 2; ++mt){
        int rr = (wave * 32 + mt * 16 + l16) * 40 + quad * 8;
        ah[mt] = *(const short8*)&Xh[rr];
        al[mt] = *(const short8*)&Xl[rr];
      }
      #pragma unroll
      for (int nt = 0; nt < 8; ++nt){
        int rr = (nt * 16 + l16) * 32 + quad * 8;
        bh[nt] = *(const short8*)&Wh[rr];
        bl[nt] = *(const short8*)&Wl[rr];
      }
      #pragma unroll
      for (int mt = 0; mt < 2; ++mt)
        #pragma unroll
        for (int nt = 0; nt < 8; ++nt){
          acc[mt][nt] = __builtin_amdgcn_mfma_f32_16x16x32_bf16(ah[mt], bh[nt], acc[mt][nt], 0,0,0);
          acc[mt][nt] = __builtin_amdgcn_mfma_f32_16x16x32_bf16(ah[mt], bl[nt], acc[mt][nt], 0,0,0);
          acc[mt][nt] = __builtin_amdgcn_mfma_f32_16x16x32_bf16(al[mt], bh[nt], acc[mt][nt], 0,0,0);
        }
    }
    __syncthreads();
  }

  // ---- phase-1 epilogue: lrelu+bias -> bf16 tile T in LDS ----
  {
    float bv[8];
    #pragma unroll
    for (int nt = 0; nt < 8; ++nt) bv[nt] = enc_b[a * H_N + nt * 16 + l16];
    #pragma unroll
    for (int mt = 0; mt < 2; ++mt)
      #pragma unroll
      for (int nt = 0; nt < 8; ++nt)
        #pragma unroll
        for (int r = 0; r < 4; ++r){
          int rl = wave * 32 + mt * 16 + quad * 4 + r;
          T[rl * 136 + nt * 16 + l16] = f2bf(lrelu(acc[mt][nt][r] + bv[nt]));
        }
  }
  __syncthreads();
  // vectorized sa_enc store from tile
  for (int c = t; c < 2048; c += 256){
    int row = c >> 4, col8 = (c & 15) * 8;
    *(uint4*)(sa_enc + ((size_t)a * B_N + row0 + row) * H_N + col8) =
        *(const uint4*)&T[row * 136 + col8];
  }

  // ---- phase 2: sels = T @ selT (single-term), BK=64 ----
  #pragma unroll
  for (int mt = 0; mt < 2; ++mt)
    #pragma unroll
    for (int nt = 0; nt < 8; ++nt) acc[mt][nt] = (floatx4){0.f,0.f,0.f,0.f};
  for (int k0 = 0; k0 < H_N; k0 += 64){
    #pragma unroll
    for (int c = t; c < 1024; c += 256)
      glds16(selH + (k0 >> 5) * 4096 + c * 8, Ws + c * 8);
    __syncthreads();
    #pragma unroll
    for (int ks = 0; ks < 64; ks += 32){
      short8 ah[2], bh[8];
      #pragma unroll
      for (int mt = 0; mt < 2; ++mt)
        ah[mt] = *(const short8*)&T[(wave * 32 + mt * 16 + l16) * 136 + k0 + ks + quad * 8];
      #pragma unroll
      for (int nt = 0; nt < 8; ++nt)
        bh[nt] = *(const short8*)&Ws[((ks >> 5) << 12) + (nt * 16 + l16) * 32 + quad * 8];
      #pragma unroll
      for (int mt = 0; mt < 2; ++mt)
        #pragma unroll
        for (int nt = 0; nt < 8; ++nt)
          acc[mt][nt] = __builtin_amdgcn_mfma_f32_16x16x32_bf16(ah[mt], bh[nt], acc[mt][nt], 0,0,0);
    }
    __syncthreads();
  }
  #pragma unroll
  for (int mt = 0; mt < 2; ++mt)
    #pragma unroll
    for (int nt = 0; nt < 8; ++nt)
      #pragma unroll
      for (int r = 0; r < 4; ++r){
        int rl = wave * 32 + mt * 16 + quad * 4 + r;
        T[rl * 136 + nt * 16 + l16] = f2bf(acc[mt][nt][r]);
      }
  __syncthreads();
  for (int c = t; c < 2048; c += 256){
    int row = c >> 4, col8 = (c & 15) * 8;
    *(uint4*)(sels + ((size_t)a * B_N + row0 + row) * H_N + col8) =
        *(const uint4*)&T[row * 136 + col8];
  }
}

// ---------------------------------------------------------------------------
// Fused kernel 2: a_enc = lrelu(BN(actions) @ aenc_w + aenc_b) [3-term, K=32]
//   keys & vals in ONE dual-accumulator loop (BK=64, single-term weights).
// bounds(256,2): dual accumulators (128 AGPR) + fragments need ~260 regs;
// tighter bounds spill (R5 lesson).
// ---------------------------------------------------------------------------
__global__ __launch_bounds__(256, 2) void k_aenc_kv(
    const float* __restrict__ actions,
    const float* __restrict__ mean, const float* __restrict__ istd,
    const u16* __restrict__ aencH, const u16* __restrict__ aencL,
    const float* __restrict__ aenc_b,
    const u16* __restrict__ keyH, const u16* __restrict__ valH,
    const float* __restrict__ val_b,
    u16* __restrict__ keys, u16* __restrict__ vals)
{
  int a = blockIdx.y; int row0 = blockIdx.x * 128; int t = threadIdx.x;
  int lane = t & 63, wave = t >> 6, l16 = lane & 15, quad = lane >> 4;
  __shared__ __align__(16) u16 S[34816];
  __shared__ __align__(16) float sc[32], sh[32];
  u16* T  = S;            // [128][136] a_enc tile; later vals tile
  u16* WK = S + 17408;    // [2][128][32] key weight tiles
  u16* WV = S + 25600;    // [2][128][32] val weight tiles
  u16* T2 = S + 17408;    // [128][136] keys tile (epilogue)

  if (t < 32){
    float m = mean[a * SAF + 128 + t], s = istd[a * SAF + 128 + t];
    sc[t] = s; sh[t] = -m * s;
  }
  floatx4 accK[2][8], accV[2][8];
  #pragma unroll
  for (int mt = 0; mt < 2; ++mt)
    #pragma unroll
    for (int nt = 0; nt < 8; ++nt){
      accK[mt][nt] = (floatx4){0.f,0.f,0.f,0.f};
      accV[mt][nt] = (floatx4){0.f,0.f,0.f,0.f};
    }
  __syncthreads();

  // ---- phase 1: aenc GEMM, K=32 single tile ----
  {
    u16* Wh1 = S;  u16* Wl1 = S + 4096;
    u16* Xh = S + 8192; u16* Xl = S + 13312;  // [128][40]
    const u16* abh = aencH + (size_t)a * 4096;
    const u16* abl = aencL + (size_t)a * 4096;
    #pragma unroll
    for (int c = t; c < 512; c += 256){
      glds16(abh + c * 8, Wh1 + c * 8);
      glds16(abl + c * 8, Wl1 + c * 8);
    }
    for (int c = t; c < 1024; c += 256){
      int r = c >> 3, kc = (c & 7) * 4;
      size_t row = (size_t)a * B_N + row0 + r;
      float4 v = *(const float4*)(actions + row * OUT_N + kc);
      float4 scv = *(const float4*)&sc[kc];
      float4 shv = *(const float4*)&sh[kc];
      float x0 = fmaf(v.x, scv.x, shv.x), x1 = fmaf(v.y, scv.y, shv.y);
      float x2 = fmaf(v.z, scv.z, shv.z), x3 = fmaf(v.w, scv.w, shv.w);
      u16 h0 = f2bf(x0), h1 = f2bf(x1), h2 = f2bf(x2), h3 = f2bf(x3);
      uint2 hv; hv.x = (u32)h0 | ((u32)h1 << 16); hv.y = (u32)h2 | ((u32)h3 << 16);
      *(uint2*)&Xh[r * 40 + kc] = hv;
      u16 l0 = f2bf(x0 - bf2f(h0)), l1 = f2bf(x1 - bf2f(h1));
      u16 l2 = f2bf(x2 - bf2f(h2)), l3 = f2bf(x3 - bf2f(h3));
      uint2 lv; lv.x = (u32)l0 | ((u32)l1 << 16); lv.y = (u32)l2 | ((u32)l3 << 16);
      *(uint2*)&Xl[r * 40 + kc] = lv;
    }
    __syncthreads();
    short8 ah[2], al[2], bh[8], bl[8];
    #pragma unroll
    for (int mt = 0; mt < 2; ++mt){
      int rr = (wave * 32 + mt * 16 + l16) * 40 + quad * 8;
      ah[mt] = *(const short8*)&Xh[rr];
      al[mt] = *(const short8*)&Xl[rr];
    }
    #pragma unroll
    for (int nt = 0; nt < 8; ++nt){
      int rr = (nt * 16 + l16) * 32 + quad * 8;
      bh[nt] = *(const short8*)&Wh1[rr];
      bl[nt] = *(const short8*)&Wl1[rr];
    }
    #pragma unroll
    for (int mt = 0; mt < 2; ++mt)
      #pragma unroll
      for (int nt = 0; nt < 8; ++nt){
        accK[mt][nt] = __builtin_amdgcn_mfma_f32_16x16x32_bf16(ah[mt], bh[nt], accK[mt][nt], 0,0,0);
        accK[mt][nt] = __builtin_amdgcn_mfma_f32_16x16x32_bf16(ah[mt], bl[nt], accK[mt][nt], 0,0,0);
        accK[mt][nt] = __builtin_amdgcn_mfma_f32_16x16x32_bf16(al[mt], bh[nt], accK[mt][nt], 0,0,0);
      }
    __syncthreads();
  }
  // a_enc -> LDS tile T; move from accK, then zero accK
  {
    float bv[8];
    #pragma unroll
    for (int nt = 0; nt < 8; ++nt) bv[nt] = aenc_b[a * H_N + nt * 16 + l16];
    #pragma unroll
    for (int mt = 0; mt < 2; ++mt)
      #pragma unroll
      for (int nt = 0; nt < 8; ++nt){
        #pragma unroll
        for (int r = 0; r < 4; ++r){
          int rl = wave * 32 + mt * 16 + quad * 4 + r;
          T[rl * 136 + nt * 16 + l16] = f2bf(lrelu(accK[mt][nt][r] + bv[nt]));
        }
        accK[mt][nt] = (floatx4){0.f,0.f,0.f,0.f};
      }
  }

  // ---- phase 2: keys + vals in one dual-acc loop (BK=64, single-term) ----
  for (int k0 = 0; k0 < H_N; k0 += 64){
    __syncthreads();
    #pragma unroll
    for (int c = t; c < 1024; c += 256){
      glds16(keyH + (k0 >> 5) * 4096 + c * 8, WK + c * 8);
      glds16(valH + (k0 >> 5) * 4096 + c * 8, WV + c * 8);
    }
    __syncthreads();
    #pragma unroll
    for (int ks = 0; ks < 64; ks += 32){
      short8 ah[2], bk[8], bv[8];
      #pragma unroll
      for (int mt = 0; mt < 2; ++mt)
        ah[mt] = *(const short8*)&T[(wave * 32 + mt * 16 + l16) * 136 + k0 + ks + quad * 8];
      #pragma unroll
      for (int nt = 0; nt < 8; ++nt){
        int rr = ((ks >> 5) << 12) + (nt * 16 + l16) * 32 + quad * 8;
        bk[nt] = *(const short8*)&WK[rr];
        bv[nt] = *(const short8*)&WV[rr];
      }
      #pragma unroll
      for (int mt = 0; mt < 2; ++mt)
        #pragma unroll
        for (int nt = 0; nt < 8; ++nt){
          accK[mt][nt] = __builtin_amdgcn_mfma_f32_16x16x32_bf16(ah[mt], bk[nt], accK[mt][nt], 0,0,0);
          accV[mt][nt] = __builtin_amdgcn_mfma_f32_16x16x32_bf16(ah[mt], bv[nt], accV[mt][nt], 0,0,0);
        }
    }
  }
  __syncthreads();
  // epilogue: vals -> T (with bias+lrelu), keys -> T2; both vectorized
  {
    float bv[8];
    #pragma unroll
    for (int nt = 0; nt < 8; ++nt) bv[nt] = val_b[nt * 16 + l16];
    #pragma unroll
    for (int mt = 0; mt < 2; ++mt)
      #pragma unroll
      for (int nt = 0; nt < 8; ++nt)
        #pragma unroll
        for (int r = 0; r < 4; ++r){
          int rl = wave * 32 + mt * 16 + quad * 4 + r;
          T[rl * 136 + nt * 16 + l16]  = f2bf(lrelu(accV[mt][nt][r] + bv[nt]));
          T2[rl * 136 + nt * 16 + l16] = f2bf(accK[mt][nt][r]);
        }
  }
  __syncthreads();
  for (int c = t; c < 2048; c += 256){
    int row = c >> 4, col8 = (c & 15) * 8;
    *(uint4*)(vals + ((size_t)a * B_N + row0 + row) * H_N + col8) =
        *(const uint4*)&T[row * 136 + col8];
    *(uint4*)(keys + ((size_t)a * B_N + row0 + row) * H_N + col8) =
        *(const uint4*)&T2[row * 136 + col8];
  }
}

// ---------------------------------------------------------------------------
// Attention. LDS tiles permuted at 16B-unit granularity:
//   U(aa,bl,kk,dg) = (bl*4+dg)*32 + kk*8 + (aa ^ (kk<<1) ^ dg)
// Old row-major layout made the si gather a 32-way bank conflict. Permuted:
// staging writes and K/V dot reads 2-way (free). Same 24 KB. `other` may
// alias `keys` (reads complete before __syncthreads; rows disjoint).
// ---------------------------------------------------------------------------
__global__ __launch_bounds__(256) void k_attn(
    const u16* __restrict__ sels, const u16* __restrict__ keys,
    const u16* __restrict__ vals, u16* __restrict__ other)
{
  int b0 = blockIdx.x * 8;
  int t = threadIdx.x;
  __shared__ __align__(16) u16 sS[8192], sK[8192], sV[8192];
  #pragma unroll
  for (int c = t; c < 1024; c += 256){
    int pr = c >> 4, uir = c & 15;
    int aa = pr & 7, bl2 = pr >> 3;
    int kk = uir >> 2, dg = uir & 3;
    int U = (bl2 * 4 + dg) * 32 + kk * 8 + (aa ^ (kk << 1) ^ dg);
    size_t go = ((size_t)aa * B_N + b0 + bl2) * KD_N;
    ((uint4*)sS)[U] = *((const uint4*)(sels + go) + uir);
    ((uint4*)sK)[U] = *((const uint4*)(keys + go) + uir);
    ((uint4*)sV)[U] = *((const uint4*)(vals + go) + uir);
  }
  __syncthreads();
  int i = t & 7, k = (t >> 3) & 3, bl = t >> 5;
  float si[32];
  #pragma unroll
  for (int dg = 0; dg < 4; ++dg){
    int U = (bl * 4 + dg) * 32 + k * 8 + (i ^ (k << 1) ^ dg);
    uint4 s4 = ((const uint4*)sS)[U];
    const u32* sp = (const u32*)&s4;
    #pragma unroll
    for (int jj = 0; jj < 4; ++jj){
      int d2 = dg * 4 + jj;
      si[2 * d2] = bf_lo(sp[jj]); si[2 * d2 + 1] = bf_hi(sp[jj]);
    }
  }
  float lg[8];
  #pragma unroll
  for (int j = 0; j < 8; ++j){
    float acc = 0.f;
    #pragma unroll
    for (int dg = 0; dg < 4; ++dg){
      int U = (bl * 4 + dg) * 32 + k * 8 + (j ^ (k << 1) ^ dg);
      uint4 k4 = ((const uint4*)sK)[U];
      const u32* kp = (const u32*)&k4;
      #pragma unroll
      for (int jj = 0; jj < 4; ++jj){
        int d2 = dg * 4 + jj;
        acc = fmaf(si[2 * d2], bf_lo(kp[jj]), acc);
        acc = fmaf(si[2 * d2 + 1], bf_hi(kp[jj]), acc);
      }
    }
    lg[j] = acc * 0.17677669529663689f;
  }
  float mx = -3.0e38f;
  #pragma unroll
  for (int j = 0; j < 8; ++j) if (j != i) mx = fmaxf(mx, lg[j]);
  float pe[8], se = 0.f;
  #pragma unroll
  for (int j = 0; j < 8; ++j){
    pe[j] = (j == i) ? 0.f : __expf(lg[j] - mx);
    se += pe[j];
  }
  float inv = 1.f / se;
  #pragma unroll
  for (int j = 0; j < 8; ++j) pe[j] *= inv;
  float o0[16], o1[16];
  #pragma unroll
  for (int d2 = 0; d2 < 16; ++d2){ o0[d2] = 0.f; o1[d2] = 0.f; }
  #pragma unroll
  for (int j = 0; j < 8; ++j){
    #pragma unroll
    for (int dg = 0; dg < 4; ++dg){
      int U = (bl * 4 + dg) * 32 + k * 8 + (j ^ (k << 1) ^ dg);
      uint4 v4 = ((const uint4*)sV)[U];
      const u32* vp = (const u32*)&v4;
      #pragma unroll
      for (int jj = 0; jj < 4; ++jj){
        int d2 = dg * 4 + jj;
        o0[d2] = fmaf(pe[j], bf_lo(vp[jj]), o0[d2]);
        o1[d2] = fmaf(pe[j], bf_hi(vp[jj]), o1[d2]);
      }
    }
  }
  __align__(16) u16 ob[32];
  #pragma unroll
  for (int d2 = 0; d2 < 16; ++d2){
    ob[2 * d2] = f2bf(o0[d2]); ob[2 * d2 + 1] = f2bf(o1[d2]);
  }
  uint4* dst = (uint4*)(other + ((size_t)i * B_N + (b0 + bl)) * KD_N + k * 32);
  const uint4* s4o = (const uint4*)ob;
  #pragma unroll
  for (int c = 0; c < 4; ++c) dst[c] = s4o[c];
}

// ---------------------------------------------------------------------------
// Critic: h = lrelu([sa_enc|other] @ c1_w + c1_b); q = h . c2_w + c2_b
// R1-proven: 256 threads, M=128, bounds(256,3) (reg budget 170 fits the
// ~148-reg floor; 512-thread variants spill -- R5). All staging via glds.
// LDS 24576 B.
// ---------------------------------------------------------------------------
__global__ __launch_bounds__(256, 3) void k_critic(
    const u16* __restrict__ sa_enc, const u16* __restrict__ other,
    const u16* __restrict__ c1H, const u16* __restrict__ c1L,
    const float* __restrict__ c1_b,
    const float* __restrict__ c2w, const float* __restrict__ c2b,
    float* __restrict__ qout)
{
  int a = blockIdx.y; int row0 = blockIdx.x * 128; int t = threadIdx.x;
  int lane = t & 63, wave = t >> 6, l16 = lane & 15, quad = lane >> 4;
  __shared__ __align__(16) u16 Xs[4096];
  __shared__ __align__(16) u16 Wh[4096];
  __shared__ __align__(16) u16 Wl[4096];
  floatx4 acc[2][8];
  #pragma unroll
  for (int mt = 0; mt < 2; ++mt)
    #pragma unroll
    for (int nt = 0; nt < 8; ++nt) acc[mt][nt] = (floatx4){0.f,0.f,0.f,0.f};
  const u16* wbh = c1H + (size_t)a * (H_N * CIN_N);
  const u16* wbl = c1L + (size_t)a * (H_N * CIN_N);

  for (int kt = 0; kt < 8; ++kt){
    const u16* th = wbh + kt * 4096;
    const u16* tl = wbl + kt * 4096;
    #pragma unroll
    for (int c = t; c < 512; c += 256){
      glds16(th + c * 8, Wh + c * 8);
      glds16(tl + c * 8, Wl + c * 8);
    }
    {
      const u16* src = (kt < 4) ? sa_enc : other;
      int kb = (kt < 4) ? kt * 32 : kt * 32 - H_N;
      #pragma unroll
      for (int c = t; c < 512; c += 256){
        int r = c >> 2, off = (c & 3) * 8;
        glds16(src + ((size_t)a * B_N + row0 + r) * H_N + kb + off, Xs + c * 8);
      }
    }
    __syncthreads();
    {
      short8 ah[2], bh[8], bl[8];
      #pragma unroll
      for (int mt = 0; mt < 2; ++mt)
        ah[mt] = *(const short8*)&Xs[(wave * 32 + mt * 16 + l16) * 32 + quad * 8];
      #pragma unroll
      for (int nt = 0; nt < 8; ++nt){
        int rr = (nt * 16 + l16) * 32 + quad * 8;
        bh[nt] = *(const short8*)&Wh[rr];
        bl[nt] = *(const short8*)&Wl[rr];
      }
      #pragma unroll
      for (int mt = 0; mt < 2; ++mt)
        #pragma unroll
        for (int nt = 0; nt < 8; ++nt){
          acc[mt][nt] = __builtin_amdgcn_mfma_f32_16x16x32_bf16(ah[mt], bh[nt], acc[mt][nt], 0,0,0);
          acc[mt][nt] = __builtin_amdgcn_mfma_f32_16x16x32_bf16(ah[mt], bl[nt], acc[mt][nt], 0,0,0);
        }
    }
    __syncthreads();
  }

  float c2r[8], bv[8];
  #pragma unroll
  for (int nt = 0; nt < 8; ++nt){
    c2r[nt] = c2w[a * H_N + nt * 16 + l16];
    bv[nt]  = c1_b[a * H_N + nt * 16 + l16];
  }
  #pragma unroll
  for (int mt = 0; mt < 2; ++mt){
    #pragma unroll
    for (int r = 0; r < 4; ++r){
      float s = 0.f;
      #pragma unroll
      for (int nt = 0; nt < 8; ++nt){
        float h = lrelu(acc[mt][nt][r] + bv[nt]);
        s = fmaf(h, c2r[nt], s);
      }
      s += __shfl_xor(s, 1);
      s += __shfl_xor(s, 2);
      s += __shfl_xor(s, 4);
      s += __shfl_xor(s, 8);
      if (l16 == 0){
        int row = row0 + wave * 32 + mt * 16 + quad * 4 + r;
        qout[(size_t)a * B_N + row] = s + c2b[a];
      }
    }
  }
}

// ---------------------------------------------------------------------------
extern "C" void kernel_launch(void* const* d_in, const int* in_sizes, int n_in,
                              void* d_out, int out_size, void* d_ws, size_t ws_size,
                              hipStream_t stream)
{
  const float* states  = (const float*)d_in[0];
  const float* actions = (const float*)d_in[1];
  const float* enc_w   = (const float*)d_in[2];
  const float* enc_b   = (const float*)d_in[3];
  const float* aenc_w  = (const float*)d_in[4];
  const float* aenc_b  = (const float*)d_in[5];
  const float* key_w   = (const float*)d_in[6];
  const float* sel_w   = (const float*)d_in[7];
  const float* val_w   = (const float*)d_in[8];
  const float* val_b   = (const float*)d_in[9];
  const float* c1_w    = (const float*)d_in[10];
  const float* c1_b    = (const float*)d_in[11];
  const float* c2_w    = (const float*)d_in[12];
  const float* c2_b    = (const float*)d_in[13];
  float* q = (float*)d_out;

  char* ws = (char*)d_ws;
  // Pack region [0, 884,736) overlaps stats partials [0, 1,310,720):
  // stats/finalize consume `part` before k_pack overwrites (sequential stream).
  u16* encH  = (u16*)(ws + 0);          // 327680 B
  u16* encL  = (u16*)(ws + 327680);     // 327680 B
  u16* aencH = (u16*)(ws + 655360);     //  65536 B
  u16* aencL = (u16*)(ws + 720896);     //  65536 B
  u16* keyH  = (u16*)(ws + 786432);     //  32768 B
  u16* selH  = (u16*)(ws + 819200);     //  32768 B
  u16* valH  = (u16*)(ws + 851968);     //  32768 B -> ends 884,736
  float* part    = (float*)ws;          // 1,310,720 B (dead after finalize)
  float* meanArr = (float*)(ws + 1310720);
  float* istdArr = (float*)(ws + 1315840);
  u16* c1H = (u16*)(ws + 1320960);      // 524288 B
  u16* c1L = (u16*)(ws + 1845248);      // 524288 B -> ends 2,369,536
  const size_t ibase = 4194304;
  const size_t BUF = (size_t)A_N * B_N * 128 * 2;   // 64 MB
  u16* sa_enc = (u16*)(ws + ibase);
  u16* sels   = (u16*)(ws + ibase + BUF);
  u16* keys   = (u16*)(ws + ibase + 2 * BUF);       // keys, later `other`
  u16* vals   = (u16*)(ws + ibase + 3 * BUF);

  k_stats<<<dim3(CHUNKS, A_N), 256, 0, stream>>>(states, actions, part);
  k_finalize<<<(A_N * SAF + 255) / 256, 256, 0, stream>>>(part, meanArr, istdArr);
  k_pack<<<(PACK_TOTAL + 255) / 256, 256, 0, stream>>>(
      enc_w, aenc_w, key_w, sel_w, val_w, c1_w,
      encH, encL, aencH, aencL, keyH, selH, valH, c1H, c1L);

  dim3 g(B_N / 128, A_N);
  k_enc_sel<<<g, 256, 0, stream>>>(states, actions, meanArr, istdArr,
                                   encH, encL, enc_b, selH, sa_enc, sels);
  k_aenc_kv<<<g, 256, 0, stream>>>(actions, meanArr, istdArr,
                                   aencH, aencL, aenc_b, keyH, valH, val_b,
                                   keys, vals);
  k_attn<<<B_N / 8, 256, 0, stream>>>(sels, keys, vals, keys);  // other -> keys
  k_critic<<<g, 256, 0, stream>>>(sa_enc, keys, c1H, c1L, c1_b, c2_w, c2_b, q);
}

// Round 8
// 503.760 us; speedup vs baseline: 1.3234x; 1.0145x over previous
//
#include <hip/hip_runtime.h>
#include <hip/hip_bf16.h>
#include <stdint.h>

// Problem constants
#define A_N 8
#define B_N 32768
#define IN_N 128
#define OUT_N 32
#define SAF 160      // IN + OUT  (= enc K, exactly 5 x 32: NO pad)
#define H_N 128
#define D_N 32
#define KD_N 128     // K*D
#define CIN_N 256    // critic input = H + K*D
#define CHUNKS 128   // stats chunks over B
#define EPSV 1e-5f

typedef unsigned int u32;
typedef unsigned short u16;
typedef __attribute__((ext_vector_type(8))) short short8;    // 8 bf16 (4 VGPRs)
typedef __attribute__((ext_vector_type(4))) float floatx4;   // MFMA C/D

// async global->LDS, 16B per lane. LDS dest = wave-uniform base + lane*16,
// so dest layout MUST be linear in lane order; source kept linear too
// (R3: permuted sources defeat VMEM coalescing). Weight tiles are packed
// tile-major [k-tile][128 n][32 k] so linear glds lands correctly.
// R2-R4: LDS XOR-swizzle cut conflicts 6.4M->2.75M but net-zero wall clock.
// R5: audit AGPR+VGPR floor before __launch_bounds__ changes (critic spilled).
// R7: f2bf via HW cvt (__float2bfloat16 -> native bf16 convert) -- the
// integer RNE sequence was ~4 VALU inst/conversion, enc_sel ~1000/thread.
// NOTE: ROCm 7.2 has NO __floats2bfloat162_rn / __float22bfloat162_rn;
// pair-pack built from two scalar casts.
typedef __attribute__((address_space(1))) void gvoid;
typedef __attribute__((address_space(3))) void lvoid;
__device__ __forceinline__ void glds16(const void* g, void* l){
  __builtin_amdgcn_global_load_lds((gvoid*)g, (lvoid*)l, 16, 0, 0);
}

__device__ __forceinline__ float bf_lo(u32 u){ return __uint_as_float(u << 16); }
__device__ __forceinline__ float bf_hi(u32 u){ return __uint_as_float(u & 0xffff0000u); }
__device__ __forceinline__ float bf2f(u16 b){ return __uint_as_float(((u32)b) << 16); }
// HW RNE conversion (identical rounding to the old integer sequence for
// finite values).
__device__ __forceinline__ u16 f2bf(float f){
  union { __hip_bfloat16 b; u16 u; } cv;
  cv.b = __float2bfloat16(f);
  return cv.u;
}
// packed pair: lo in bits [15:0], hi in bits [31:16]
__device__ __forceinline__ u32 f2bf2(float lo, float hi){
  return (u32)f2bf(lo) | ((u32)f2bf(hi) << 16);
}
__device__ __forceinline__ float lrelu(float x){ return x > 0.f ? x : 0.01f * x; }

// ---------------------------------------------------------------------------
// Stage 1: BN statistics (sum, sumsq) per (agent, feature).
// states loop vectorized to float4.
// ---------------------------------------------------------------------------
__global__ __launch_bounds__(256) void k_stats(
    const float* __restrict__ states, const float* __restrict__ actions,
    float* __restrict__ part)
{
  int a = blockIdx.y;
  int chunk = blockIdx.x;
  int t = threadIdx.x;
  int r0 = chunk * (B_N / CHUNKS);   // 256 rows per chunk
  __shared__ __align__(16) float red[2048];
  {
    int f4 = t & 31, g = t >> 5;
    const float4* p = (const float4*)(states + ((size_t)a * B_N + r0 + g) * IN_N) + f4;
    float4 s1 = {0.f,0.f,0.f,0.f}, s2 = {0.f,0.f,0.f,0.f};
    for (int it = 0; it < 32; ++it){
      float4 v = p[(size_t)(8 * it) * (IN_N / 4)];
      s1.x += v.x; s1.y += v.y; s1.z += v.z; s1.w += v.w;
      s2.x = fmaf(v.x, v.x, s2.x); s2.y = fmaf(v.y, v.y, s2.y);
      s2.z = fmaf(v.z, v.z, s2.z); s2.w = fmaf(v.w, v.w, s2.w);
    }
    ((float4*)red)[t] = s1;
    ((float4*)red)[256 + t] = s2;
    __syncthreads();
    if (t < 128){
      int ff4 = t >> 2, j = t & 3;
      float a1 = 0.f, a2 = 0.f;
      #pragma unroll
      for (int gg = 0; gg < 8; ++gg){
        a1 += red[(ff4 + 32 * gg) * 4 + j];
        a2 += red[(256 + ff4 + 32 * gg) * 4 + j];
      }
      size_t o = (((size_t)a * CHUNKS + chunk) * SAF + t) * 2;
      part[o] = a1; part[o + 1] = a2;
    }
    __syncthreads();
  }
  {
    int f = t & 31, g = t >> 5;
    const float* p = actions + ((size_t)a * B_N + r0 + g) * OUT_N + f;
    float s1 = 0.f, s2 = 0.f;
    for (int it = 0; it < 32; ++it){
      float v = p[(size_t)(8 * it) * OUT_N];
      s1 += v; s2 += v * v;
    }
    red[t] = s1; red[256 + t] = s2;
    __syncthreads();
    if (t < 32){
      float a1 = 0.f, a2 = 0.f;
      #pragma unroll
      for (int gg = 0; gg < 8; ++gg){
        a1 += red[t + 32 * gg];
        a2 += red[256 + t + 32 * gg];
      }
      size_t o = (((size_t)a * CHUNKS + chunk) * SAF + 128 + t) * 2;
      part[o] = a1; part[o + 1] = a2;
    }
  }
}

__global__ void k_finalize(const float* __restrict__ part,
                           float* __restrict__ meanArr, float* __restrict__ istdArr)
{
  int idx = blockIdx.x * blockDim.x + threadIdx.x;
  if (idx >= A_N * SAF) return;
  int a = idx / SAF, f = idx % SAF;
  float s1 = 0.f, s2 = 0.f;
  for (int c = 0; c < CHUNKS; ++c){
    size_t o = (((size_t)a * CHUNKS + c) * SAF + f) * 2;
    s1 += part[o]; s2 += part[o + 1];
  }
  float m = s1 * (1.f / B_N);
  float v = s2 * (1.f / B_N) - m * m;
  if (v < 0.f) v = 0.f;
  meanArr[idx] = m;
  istdArr[idx] = rsqrtf(v + EPSV);
}

// ---------------------------------------------------------------------------
// Weight pre-pack, TILE-MAJOR for global_load_lds:
//   layout = [k-tile][128 n][32 k] contiguous (4096 u16 = 8192 B per tile).
// enc/c1: hi/lo bf16 pairs; key/sel/val: single bf16.
// ---------------------------------------------------------------------------
__device__ __forceinline__ void packpair(float w, u16* __restrict__ dh,
                                         u16* __restrict__ dl, int i){
  u16 h = f2bf(w);
  dh[i] = h;
  dl[i] = f2bf(w - bf2f(h));
}

__global__ __launch_bounds__(256) void k_pack(
    const float* __restrict__ enc_w, const float* __restrict__ aenc_w,
    const float* __restrict__ key_w, const float* __restrict__ sel_w,
    const float* __restrict__ val_w, const float* __restrict__ c1_w,
    u16* __restrict__ encH, u16* __restrict__ encL,
    u16* __restrict__ aencH, u16* __restrict__ aencL,
    u16* __restrict__ keyH, u16* __restrict__ selH, u16* __restrict__ valH,
    u16* __restrict__ c1H, u16* __restrict__ c1L)
{
  int i = blockIdx.x * 256 + threadIdx.x;
  const int S0 = A_N * H_N * SAF;      // 163840 enc (5 tiles/agent)
  const int S1 = A_N * H_N * OUT_N;    // 32768 aenc
  const int S2 = KD_N * H_N;           // 16384 per key/sel/val (4 tiles)
  const int S5 = A_N * H_N * CIN_N;    // 262144 c1 (8 tiles/agent)
  if (i < S0){
    int a = i / (H_N * SAF); int r = i % (H_N * SAF);
    int tile = r >> 12; int rr = r & 4095;
    int n = rr >> 5; int kk = rr & 31;
    int kg = tile * 32 + kk;
    packpair(enc_w[((size_t)a * SAF + kg) * H_N + n], encH, encL, i);
    return;
  }
  i -= S0;
  if (i < S1){
    int a = i >> 12; int rr = i & 4095;
    int n = rr >> 5; int k = rr & 31;
    packpair(aenc_w[((size_t)a * OUT_N + k) * H_N + n], aencH, aencL, i);
    return;
  }
  i -= S1;
  if (i < 3 * S2){
    int which = i / S2; int j = i % S2;
    int tile = j >> 12; int rr = j & 4095;
    int n = rr >> 5; int kk = rr & 31;
    int kg = tile * 32 + kk;
    const float* w = (which == 0) ? key_w : ((which == 1) ? sel_w : val_w);
    u16* dh = (which == 0) ? keyH : ((which == 1) ? selH : valH);
    dh[j] = f2bf(w[(((size_t)(n >> 5)) * H_N + kg) * D_N + (n & 31)]);
    return;
  }
  i -= 3 * S2;
  if (i < S5){
    int a = i >> 15; int r = i & 32767;
    int tile = r >> 12; int rr = r & 4095;
    int n = rr >> 5; int kk = rr & 31;
    int kg = tile * 32 + kk;
    packpair(c1_w[((size_t)a * CIN_N + kg) * H_N + n], c1H, c1L, i);
  }
}
#define PACK_TOTAL (A_N*H_N*SAF + A_N*H_N*OUT_N + 3*KD_N*H_N + A_N*H_N*CIN_N)

// ---------------------------------------------------------------------------
// Fused kernel 1: sa_enc = lrelu(BN(concat) @ enc_w + enc_b)  [3-term, BK=32,
//   K=160], sels = sa_enc @ sel_w [1-term, BK=64].
// R1-proven synchronous structure; transform uses HW bf16 cvt.
// ---------------------------------------------------------------------------
__global__ __launch_bounds__(256, 3) void k_enc_sel(
    const float* __restrict__ states, const float* __restrict__ actions,
    const float* __restrict__ mean, const float* __restrict__ istd,
    const u16* __restrict__ encH, const u16* __restrict__ encL,
    const float* __restrict__ enc_b,
    const u16* __restrict__ selH,
    u16* __restrict__ sa_enc, u16* __restrict__ sels)
{
  int a = blockIdx.y; int row0 = blockIdx.x * 128; int t = threadIdx.x;
  int lane = t & 63, wave = t >> 6, l16 = lane & 15, quad = lane >> 4;
  __shared__ __align__(16) u16 S[25600];
  __shared__ __align__(16) float sc[160], sh[160];
  u16* Wh = S;            // [128][32] enc weight hi tile (phase 1)
  u16* Wl = S + 4096;     // [128][32]
  u16* Xh = S + 8192;     // [128][40]
  u16* Xl = S + 13312;    // [128][40]
  u16* T  = S;            // [128][136] (phase-1 output / phase-2 A)
  u16* Ws = S + 17408;    // [2][128][32] sel weight tiles (phase 2)

  if (t < SAF){
    float m = mean[a * SAF + t], s = istd[a * SAF + t];
    sc[t] = s; sh[t] = -m * s;
  }
  floatx4 acc[2][8];
  #pragma unroll
  for (int mt = 0; mt < 2; ++mt)
    #pragma unroll
    for (int nt = 0; nt < 8; ++nt) acc[mt][nt] = (floatx4){0.f,0.f,0.f,0.f};
  const u16* ebh = encH + (size_t)a * (H_N * SAF);
  const u16* ebl = encL + (size_t)a * (H_N * SAF);
  __syncthreads();

  // ---- phase 1: enc GEMM (3-term split), K=160, BK=32 ----
  for (int k0 = 0; k0 < SAF; k0 += 32){
    const u16* th = ebh + (k0 >> 5) * 4096;
    const u16* tl = ebl + (k0 >> 5) * 4096;
    #pragma unroll
    for (int c = t; c < 512; c += 256){
      glds16(th + c * 8, Wh + c * 8);
      glds16(tl + c * 8, Wl + c * 8);
    }
    for (int c = t; c < 1024; c += 256){
      int r = c >> 3, kc = (c & 7) * 4, f = k0 + kc;
      size_t row = (size_t)a * B_N + row0 + r;
      float4 v;
      if (f < IN_N) v = *(const float4*)(states + row * IN_N + f);
      else          v = *(const float4*)(actions + row * OUT_N + (f - IN_N));
      float4 scv = *(const float4*)&sc[f];
      float4 shv = *(const float4*)&sh[f];
      float x0 = fmaf(v.x, scv.x, shv.x), x1 = fmaf(v.y, scv.y, shv.y);
      float x2 = fmaf(v.z, scv.z, shv.z), x3 = fmaf(v.w, scv.w, shv.w);
      uint2 hv; hv.x = f2bf2(x0, x1); hv.y = f2bf2(x2, x3);
      *(uint2*)&Xh[r * 40 + kc] = hv;
      uint2 lv;
      lv.x = f2bf2(x0 - bf_lo(hv.x), x1 - bf_hi(hv.x));
      lv.y = f2bf2(x2 - bf_lo(hv.y), x3 - bf_hi(hv.y));
      *(uint2*)&Xl[r * 40 + kc] = lv;
    }
    __syncthreads();
    {
      short8 ah[2], al[2], bh[8], bl[8];
      #pragma unroll
      for (int mt = 0; mt < 2; ++mt){
        int rr = (wave * 32 + mt * 16 + l16) * 40 + quad * 8;
        ah[mt] = *(const short8*)&Xh[rr];
        al[mt] = *(const short8*)&Xl[rr];
      }
      #pragma unroll
      for (int nt = 0; nt < 8; ++nt){
        int rr = (nt * 16 + l16) * 32 + quad * 8;
        bh[nt] = *(const short8*)&Wh[rr];
        bl[nt] = *(const short8*)&Wl[rr];
      }
      #pragma unroll
      for (int mt = 0; mt < 2; ++mt)
        #pragma unroll
        for (int nt = 0; nt < 8; ++nt){
          acc[mt][nt] = __builtin_amdgcn_mfma_f32_16x16x32_bf16(ah[mt], bh[nt], acc[mt][nt], 0,0,0);
          acc[mt][nt] = __builtin_amdgcn_mfma_f32_16x16x32_bf16(ah[mt], bl[nt], acc[mt][nt], 0,0,0);
          acc[mt][nt] = __builtin_amdgcn_mfma_f32_16x16x32_bf16(al[mt], bh[nt], acc[mt][nt], 0,0,0);
        }
    }
    __syncthreads();
  }

  // ---- phase-1 epilogue: lrelu+bias -> bf16 tile T in LDS ----
  {
    float bv[8];
    #pragma unroll
    for (int nt = 0; nt < 8; ++nt) bv[nt] = enc_b[a * H_N + nt * 16 + l16];
    #pragma unroll
    for (int mt = 0; mt < 2; ++mt)
      #pragma unroll
      for (int nt = 0; nt < 8; ++nt)
        #pragma unroll
        for (int r = 0; r < 4; ++r){
          int rl = wave * 32 + mt * 16 + quad * 4 + r;
          T[rl * 136 + nt * 16 + l16] = f2bf(lrelu(acc[mt][nt][r] + bv[nt]));
        }
  }
  __syncthreads();
  // vectorized sa_enc store from tile
  for (int c = t; c < 2048; c += 256){
    int row = c >> 4, col8 = (c & 15) * 8;
    *(uint4*)(sa_enc + ((size_t)a * B_N + row0 + row) * H_N + col8) =
        *(const uint4*)&T[row * 136 + col8];
  }

  // ---- phase 2: sels = T @ selT (single-term), BK=64 ----
  #pragma unroll
  for (int mt = 0; mt < 2; ++mt)
    #pragma unroll
    for (int nt = 0; nt < 8; ++nt) acc[mt][nt] = (floatx4){0.f,0.f,0.f,0.f};
  for (int k0 = 0; k0 < H_N; k0 += 64){
    #pragma unroll
    for (int c = t; c < 1024; c += 256)
      glds16(selH + (k0 >> 5) * 4096 + c * 8, Ws + c * 8);
    __syncthreads();
    #pragma unroll
    for (int ks = 0; ks < 64; ks += 32){
      short8 ah[2], bh[8];
      #pragma unroll
      for (int mt = 0; mt < 2; ++mt)
        ah[mt] = *(const short8*)&T[(wave * 32 + mt * 16 + l16) * 136 + k0 + ks + quad * 8];
      #pragma unroll
      for (int nt = 0; nt < 8; ++nt)
        bh[nt] = *(const short8*)&Ws[((ks >> 5) << 12) + (nt * 16 + l16) * 32 + quad * 8];
      #pragma unroll
      for (int mt = 0; mt < 2; ++mt)
        #pragma unroll
        for (int nt = 0; nt < 8; ++nt)
          acc[mt][nt] = __builtin_amdgcn_mfma_f32_16x16x32_bf16(ah[mt], bh[nt], acc[mt][nt], 0,0,0);
    }
    __syncthreads();
  }
  #pragma unroll
  for (int mt = 0; mt < 2; ++mt)
    #pragma unroll
    for (int nt = 0; nt < 8; ++nt)
      #pragma unroll
      for (int r = 0; r < 4; ++r){
        int rl = wave * 32 + mt * 16 + quad * 4 + r;
        T[rl * 136 + nt * 16 + l16] = f2bf(acc[mt][nt][r]);
      }
  __syncthreads();
  for (int c = t; c < 2048; c += 256){
    int row = c >> 4, col8 = (c & 15) * 8;
    *(uint4*)(sels + ((size_t)a * B_N + row0 + row) * H_N + col8) =
        *(const uint4*)&T[row * 136 + col8];
  }
}

// ---------------------------------------------------------------------------
// Fused kernel 2: a_enc = lrelu(BN(actions) @ aenc_w + aenc_b) [3-term, K=32]
//   keys & vals in ONE dual-accumulator loop (BK=64, single-term weights).
// bounds(256,2): dual accumulators need ~260 regs; tighter bounds spill (R5).
// ---------------------------------------------------------------------------
__global__ __launch_bounds__(256, 2) void k_aenc_kv(
    const float* __restrict__ actions,
    const float* __restrict__ mean, const float* __restrict__ istd,
    const u16* __restrict__ aencH, const u16* __restrict__ aencL,
    const float* __restrict__ aenc_b,
    const u16* __restrict__ keyH, const u16* __restrict__ valH,
    const float* __restrict__ val_b,
    u16* __restrict__ keys, u16* __restrict__ vals)
{
  int a = blockIdx.y; int row0 = blockIdx.x * 128; int t = threadIdx.x;
  int lane = t & 63, wave = t >> 6, l16 = lane & 15, quad = lane >> 4;
  __shared__ __align__(16) u16 S[34816];
  __shared__ __align__(16) float sc[32], sh[32];
  u16* T  = S;            // [128][136] a_enc tile; later vals tile
  u16* WK = S + 17408;    // [2][128][32] key weight tiles
  u16* WV = S + 25600;    // [2][128][32] val weight tiles
  u16* T2 = S + 17408;    // [128][136] keys tile (epilogue)

  if (t < 32){
    float m = mean[a * SAF + 128 + t], s = istd[a * SAF + 128 + t];
    sc[t] = s; sh[t] = -m * s;
  }
  floatx4 accK[2][8], accV[2][8];
  #pragma unroll
  for (int mt = 0; mt < 2; ++mt)
    #pragma unroll
    for (int nt = 0; nt < 8; ++nt){
      accK[mt][nt] = (floatx4){0.f,0.f,0.f,0.f};
      accV[mt][nt] = (floatx4){0.f,0.f,0.f,0.f};
    }
  __syncthreads();

  // ---- phase 1: aenc GEMM, K=32 single tile ----
  {
    u16* Wh1 = S;  u16* Wl1 = S + 4096;
    u16* Xh = S + 8192; u16* Xl = S + 13312;  // [128][40]
    const u16* abh = aencH + (size_t)a * 4096;
    const u16* abl = aencL + (size_t)a * 4096;
    #pragma unroll
    for (int c = t; c < 512; c += 256){
      glds16(abh + c * 8, Wh1 + c * 8);
      glds16(abl + c * 8, Wl1 + c * 8);
    }
    for (int c = t; c < 1024; c += 256){
      int r = c >> 3, kc = (c & 7) * 4;
      size_t row = (size_t)a * B_N + row0 + r;
      float4 v = *(const float4*)(actions + row * OUT_N + kc);
      float4 scv = *(const float4*)&sc[kc];
      float4 shv = *(const float4*)&sh[kc];
      float x0 = fmaf(v.x, scv.x, shv.x), x1 = fmaf(v.y, scv.y, shv.y);
      float x2 = fmaf(v.z, scv.z, shv.z), x3 = fmaf(v.w, scv.w, shv.w);
      uint2 hv; hv.x = f2bf2(x0, x1); hv.y = f2bf2(x2, x3);
      *(uint2*)&Xh[r * 40 + kc] = hv;
      uint2 lv;
      lv.x = f2bf2(x0 - bf_lo(hv.x), x1 - bf_hi(hv.x));
      lv.y = f2bf2(x2 - bf_lo(hv.y), x3 - bf_hi(hv.y));
      *(uint2*)&Xl[r * 40 + kc] = lv;
    }
    __syncthreads();
    short8 ah[2], al[2], bh[8], bl[8];
    #pragma unroll
    for (int mt = 0; mt < 2; ++mt){
      int rr = (wave * 32 + mt * 16 + l16) * 40 + quad * 8;
      ah[mt] = *(const short8*)&Xh[rr];
      al[mt] = *(const short8*)&Xl[rr];
    }
    #pragma unroll
    for (int nt = 0; nt < 8; ++nt){
      int rr = (nt * 16 + l16) * 32 + quad * 8;
      bh[nt] = *(const short8*)&Wh1[rr];
      bl[nt] = *(const short8*)&Wl1[rr];
    }
    #pragma unroll
    for (int mt = 0; mt < 2; ++mt)
      #pragma unroll
      for (int nt = 0; nt < 8; ++nt){
        accK[mt][nt] = __builtin_amdgcn_mfma_f32_16x16x32_bf16(ah[mt], bh[nt], accK[mt][nt], 0,0,0);
        accK[mt][nt] = __builtin_amdgcn_mfma_f32_16x16x32_bf16(ah[mt], bl[nt], accK[mt][nt], 0,0,0);
        accK[mt][nt] = __builtin_amdgcn_mfma_f32_16x16x32_bf16(al[mt], bh[nt], accK[mt][nt], 0,0,0);
      }
    __syncthreads();
  }
  // a_enc -> LDS tile T; move from accK, then zero accK
  {
    float bv[8];
    #pragma unroll
    for (int nt = 0; nt < 8; ++nt) bv[nt] = aenc_b[a * H_N + nt * 16 + l16];
    #pragma unroll
    for (int mt = 0; mt < 2; ++mt)
      #pragma unroll
      for (int nt = 0; nt < 8; ++nt){
        #pragma unroll
        for (int r = 0; r < 4; ++r){
          int rl = wave * 32 + mt * 16 + quad * 4 + r;
          T[rl * 136 + nt * 16 + l16] = f2bf(lrelu(accK[mt][nt][r] + bv[nt]));
        }
        accK[mt][nt] = (floatx4){0.f,0.f,0.f,0.f};
      }
  }

  // ---- phase 2: keys + vals in one dual-acc loop (BK=64, single-term) ----
  for (int k0 = 0; k0 < H_N; k0 += 64){
    __syncthreads();
    #pragma unroll
    for (int c = t; c < 1024; c += 256){
      glds16(keyH + (k0 >> 5) * 4096 + c * 8, WK + c * 8);
      glds16(valH + (k0 >> 5) * 4096 + c * 8, WV + c * 8);
    }
    __syncthreads();
    #pragma unroll
    for (int ks = 0; ks < 64; ks += 32){
      short8 ah[2], bk[8], bv[8];
      #pragma unroll
      for (int mt = 0; mt < 2; ++mt)
        ah[mt] = *(const short8*)&T[(wave * 32 + mt * 16 + l16) * 136 + k0 + ks + quad * 8];
      #pragma unroll
      for (int nt = 0; nt < 8; ++nt){
        int rr = ((ks >> 5) << 12) + (nt * 16 + l16) * 32 + quad * 8;
        bk[nt] = *(const short8*)&WK[rr];
        bv[nt] = *(const short8*)&WV[rr];
      }
      #pragma unroll
      for (int mt = 0; mt < 2; ++mt)
        #pragma unroll
        for (int nt = 0; nt < 8; ++nt){
          accK[mt][nt] = __builtin_amdgcn_mfma_f32_16x16x32_bf16(ah[mt], bk[nt], accK[mt][nt], 0,0,0);
          accV[mt][nt] = __builtin_amdgcn_mfma_f32_16x16x32_bf16(ah[mt], bv[nt], accV[mt][nt], 0,0,0);
        }
    }
  }
  __syncthreads();
  // epilogue: vals -> T (with bias+lrelu), keys -> T2; both vectorized
  {
    float bv[8];
    #pragma unroll
    for (int nt = 0; nt < 8; ++nt) bv[nt] = val_b[nt * 16 + l16];
    #pragma unroll
    for (int mt = 0; mt < 2; ++mt)
      #pragma unroll
      for (int nt = 0; nt < 8; ++nt)
        #pragma unroll
        for (int r = 0; r < 4; ++r){
          int rl = wave * 32 + mt * 16 + quad * 4 + r;
          T[rl * 136 + nt * 16 + l16]  = f2bf(lrelu(accV[mt][nt][r] + bv[nt]));
          T2[rl * 136 + nt * 16 + l16] = f2bf(accK[mt][nt][r]);
        }
  }
  __syncthreads();
  for (int c = t; c < 2048; c += 256){
    int row = c >> 4, col8 = (c & 15) * 8;
    *(uint4*)(vals + ((size_t)a * B_N + row0 + row) * H_N + col8) =
        *(const uint4*)&T[row * 136 + col8];
    *(uint4*)(keys + ((size_t)a * B_N + row0 + row) * H_N + col8) =
        *(const uint4*)&T2[row * 136 + col8];
  }
}

// ---------------------------------------------------------------------------
// Attention. LDS tiles permuted at 16B-unit granularity:
//   U(aa,bl,kk,dg) = (bl*4+dg)*32 + kk*8 + (aa ^ (kk<<1) ^ dg)
// (fixes the old 32-way si-gather conflict). Output pack via HW cvt.
// `other` may alias `keys` (reads complete before __syncthreads; rows
// disjoint across blocks).
// ---------------------------------------------------------------------------
__global__ __launch_bounds__(256) void k_attn(
    const u16* __restrict__ sels, const u16* __restrict__ keys,
    const u16* __restrict__ vals, u16* __restrict__ other)
{
  int b0 = blockIdx.x * 8;
  int t = threadIdx.x;
  __shared__ __align__(16) u16 sS[8192], sK[8192], sV[8192];
  #pragma unroll
  for (int c = t; c < 1024; c += 256){
    int pr = c >> 4, uir = c & 15;
    int aa = pr & 7, bl2 = pr >> 3;
    int kk = uir >> 2, dg = uir & 3;
    int U = (bl2 * 4 + dg) * 32 + kk * 8 + (aa ^ (kk << 1) ^ dg);
    size_t go = ((size_t)aa * B_N + b0 + bl2) * KD_N;
    ((uint4*)sS)[U] = *((const uint4*)(sels + go) + uir);
    ((uint4*)sK)[U] = *((const uint4*)(keys + go) + uir);
    ((uint4*)sV)[U] = *((const uint4*)(vals + go) + uir);
  }
  __syncthreads();
  int i = t & 7, k = (t >> 3) & 3, bl = t >> 5;
  float si[32];
  #pragma unroll
  for (int dg = 0; dg < 4; ++dg){
    int U = (bl * 4 + dg) * 32 + k * 8 + (i ^ (k << 1) ^ dg);
    uint4 s4 = ((const uint4*)sS)[U];
    const u32* sp = (const u32*)&s4;
    #pragma unroll
    for (int jj = 0; jj < 4; ++jj){
      int d2 = dg * 4 + jj;
      si[2 * d2] = bf_lo(sp[jj]); si[2 * d2 + 1] = bf_hi(sp[jj]);
    }
  }
  float lg[8];
  #pragma unroll
  for (int j = 0; j < 8; ++j){
    float acc = 0.f;
    #pragma unroll
    for (int dg = 0; dg < 4; ++dg){
      int U = (bl * 4 + dg) * 32 + k * 8 + (j ^ (k << 1) ^ dg);
      uint4 k4 = ((const uint4*)sK)[U];
      const u32* kp = (const u32*)&k4;
      #pragma unroll
      for (int jj = 0; jj < 4; ++jj){
        int d2 = dg * 4 + jj;
        acc = fmaf(si[2 * d2], bf_lo(kp[jj]), acc);
        acc = fmaf(si[2 * d2 + 1], bf_hi(kp[jj]), acc);
      }
    }
    lg[j] = acc * 0.17677669529663689f;
  }
  float mx = -3.0e38f;
  #pragma unroll
  for (int j = 0; j < 8; ++j) if (j != i) mx = fmaxf(mx, lg[j]);
  float pe[8], se = 0.f;
  #pragma unroll
  for (int j = 0; j < 8; ++j){
    pe[j] = (j == i) ? 0.f : __expf(lg[j] - mx);
    se += pe[j];
  }
  float inv = 1.f / se;
  #pragma unroll
  for (int j = 0; j < 8; ++j) pe[j] *= inv;
  float o0[16], o1[16];
  #pragma unroll
  for (int d2 = 0; d2 < 16; ++d2){ o0[d2] = 0.f; o1[d2] = 0.f; }
  #pragma unroll
  for (int j = 0; j < 8; ++j){
    #pragma unroll
    for (int dg = 0; dg < 4; ++dg){
      int U = (bl * 4 + dg) * 32 + k * 8 + (j ^ (k << 1) ^ dg);
      uint4 v4 = ((const uint4*)sV)[U];
      const u32* vp = (const u32*)&v4;
      #pragma unroll
      for (int jj = 0; jj < 4; ++jj){
        int d2 = dg * 4 + jj;
        o0[d2] = fmaf(pe[j], bf_lo(vp[jj]), o0[d2]);
        o1[d2] = fmaf(pe[j], bf_hi(vp[jj]), o1[d2]);
      }
    }
  }
  __align__(16) u16 ob[32];
  #pragma unroll
  for (int d2 = 0; d2 < 16; ++d2)
    ((u32*)ob)[d2] = f2bf2(o0[d2], o1[d2]);
  uint4* dst = (uint4*)(other + ((size_t)i * B_N + (b0 + bl)) * KD_N + k * 32);
  const uint4* s4o = (const uint4*)ob;
  #pragma unroll
  for (int c = 0; c < 4; ++c) dst[c] = s4o[c];
}

// ---------------------------------------------------------------------------
// Critic: h = lrelu([sa_enc|other] @ c1_w + c1_b); q = h . c2_w + c2_b
// R1-proven: 256 threads, M=128, bounds(256,3). All staging via glds.
// LDS 24576 B.
// ---------------------------------------------------------------------------
__global__ __launch_bounds__(256, 3) void k_critic(
    const u16* __restrict__ sa_enc, const u16* __restrict__ other,
    const u16* __restrict__ c1H, const u16* __restrict__ c1L,
    const float* __restrict__ c1_b,
    const float* __restrict__ c2w, const float* __restrict__ c2b,
    float* __restrict__ qout)
{
  int a = blockIdx.y; int row0 = blockIdx.x * 128; int t = threadIdx.x;
  int lane = t & 63, wave = t >> 6, l16 = lane & 15, quad = lane >> 4;
  __shared__ __align__(16) u16 Xs[4096];
  __shared__ __align__(16) u16 Wh[4096];
  __shared__ __align__(16) u16 Wl[4096];
  floatx4 acc[2][8];
  #pragma unroll
  for (int mt = 0; mt < 2; ++mt)
    #pragma unroll
    for (int nt = 0; nt < 8; ++nt) acc[mt][nt] = (floatx4){0.f,0.f,0.f,0.f};
  const u16* wbh = c1H + (size_t)a * (H_N * CIN_N);
  const u16* wbl = c1L + (size_t)a * (H_N * CIN_N);

  for (int kt = 0; kt < 8; ++kt){
    const u16* th = wbh + kt * 4096;
    const u16* tl = wbl + kt * 4096;
    #pragma unroll
    for (int c = t; c < 512; c += 256){
      glds16(th + c * 8, Wh + c * 8);
      glds16(tl + c * 8, Wl + c * 8);
    }
    {
      const u16* src = (kt < 4) ? sa_enc : other;
      int kb = (kt < 4) ? kt * 32 : kt * 32 - H_N;
      #pragma unroll
      for (int c = t; c < 512; c += 256){
        int r = c >> 2, off = (c & 3) * 8;
        glds16(src + ((size_t)a * B_N + row0 + r) * H_N + kb + off, Xs + c * 8);
      }
    }
    __syncthreads();
    {
      short8 ah[2], bh[8], bl[8];
      #pragma unroll
      for (int mt = 0; mt < 2; ++mt)
        ah[mt] = *(const short8*)&Xs[(wave * 32 + mt * 16 + l16) * 32 + quad * 8];
      #pragma unroll
      for (int nt = 0; nt < 8; ++nt){
        int rr = (nt * 16 + l16) * 32 + quad * 8;
        bh[nt] = *(const short8*)&Wh[rr];
        bl[nt] = *(const short8*)&Wl[rr];
      }
      #pragma unroll
      for (int mt = 0; mt < 2; ++mt)
        #pragma unroll
        for (int nt = 0; nt < 8; ++nt){
          acc[mt][nt] = __builtin_amdgcn_mfma_f32_16x16x32_bf16(ah[mt], bh[nt], acc[mt][nt], 0,0,0);
          acc[mt][nt] = __builtin_amdgcn_mfma_f32_16x16x32_bf16(ah[mt], bl[nt], acc[mt][nt], 0,0,0);
        }
    }
    __syncthreads();
  }

  float c2r[8], bv[8];
  #pragma unroll
  for (int nt = 0; nt < 8; ++nt){
    c2r[nt] = c2w[a * H_N + nt * 16 + l16];
    bv[nt]  = c1_b[a * H_N + nt * 16 + l16];
  }
  #pragma unroll
  for (int mt = 0; mt < 2; ++mt){
    #pragma unroll
    for (int r = 0; r < 4; ++r){
      float s = 0.f;
      #pragma unroll
      for (int nt = 0; nt < 8; ++nt){
        float h = lrelu(acc[mt][nt][r] + bv[nt]);
        s = fmaf(h, c2r[nt], s);
      }
      s += __shfl_xor(s, 1);
      s += __shfl_xor(s, 2);
      s += __shfl_xor(s, 4);
      s += __shfl_xor(s, 8);
      if (l16 == 0){
        int row = row0 + wave * 32 + mt * 16 + quad * 4 + r;
        qout[(size_t)a * B_N + row] = s + c2b[a];
      }
    }
  }
}

// ---------------------------------------------------------------------------
extern "C" void kernel_launch(void* const* d_in, const int* in_sizes, int n_in,
                              void* d_out, int out_size, void* d_ws, size_t ws_size,
                              hipStream_t stream)
{
  const float* states  = (const float*)d_in[0];
  const float* actions = (const float*)d_in[1];
  const float* enc_w   = (const float*)d_in[2];
  const float* enc_b   = (const float*)d_in[3];
  const float* aenc_w  = (const float*)d_in[4];
  const float* aenc_b  = (const float*)d_in[5];
  const float* key_w   = (const float*)d_in[6];
  const float* sel_w   = (const float*)d_in[7];
  const float* val_w   = (const float*)d_in[8];
  const float* val_b   = (const float*)d_in[9];
  const float* c1_w    = (const float*)d_in[10];
  const float* c1_b    = (const float*)d_in[11];
  const float* c2_w    = (const float*)d_in[12];
  const float* c2_b    = (const float*)d_in[13];
  float* q = (float*)d_out;

  char* ws = (char*)d_ws;
  // Pack region [0, 884,736) overlaps stats partials [0, 1,310,720):
  // stats/finalize consume `part` before k_pack overwrites (sequential stream).
  u16* encH  = (u16*)(ws + 0);          // 327680 B
  u16* encL  = (u16*)(ws + 327680);     // 327680 B
  u16* aencH = (u16*)(ws + 655360);     //  65536 B
  u16* aencL = (u16*)(ws + 720896);     //  65536 B
  u16* keyH  = (u16*)(ws + 786432);     //  32768 B
  u16* selH  = (u16*)(ws + 819200);     //  32768 B
  u16* valH  = (u16*)(ws + 851968);     //  32768 B -> ends 884,736
  float* part    = (float*)ws;          // 1,310,720 B (dead after finalize)
  float* meanArr = (float*)(ws + 1310720);
  float* istdArr = (float*)(ws + 1315840);
  u16* c1H = (u16*)(ws + 1320960);      // 524288 B
  u16* c1L = (u16*)(ws + 1845248);      // 524288 B -> ends 2,369,536
  const size_t ibase = 4194304;
  const size_t BUF = (size_t)A_N * B_N * 128 * 2;   // 64 MB
  u16* sa_enc = (u16*)(ws + ibase);
  u16* sels   = (u16*)(ws + ibase + BUF);
  u16* keys   = (u16*)(ws + ibase + 2 * BUF);       // keys, later `other`
  u16* vals   = (u16*)(ws + ibase + 3 * BUF);

  k_stats<<<dim3(CHUNKS, A_N), 256, 0, stream>>>(states, actions, part);
  k_finalize<<<(A_N * SAF + 255) / 256, 256, 0, stream>>>(part, meanArr, istdArr);
  k_pack<<<(PACK_TOTAL + 255) / 256, 256, 0, stream>>>(
      enc_w, aenc_w, key_w, sel_w, val_w, c1_w,
      encH, encL, aencH, aencL, keyH, selH, valH, c1H, c1L);

  dim3 g(B_N / 128, A_N);
  k_enc_sel<<<g, 256, 0, stream>>>(states, actions, meanArr, istdArr,
                                   encH, encL, enc_b, selH, sa_enc, sels);
  k_aenc_kv<<<g, 256, 0, stream>>>(actions, meanArr, istdArr,
                                   aencH, aencL, aenc_b, keyH, valH, val_b,
                                   keys, vals);
  k_attn<<<B_N / 8, 256, 0, stream>>>(sels, keys, vals, keys);  // other -> keys
  k_critic<<<g, 256, 0, stream>>>(sa_enc, keys, c1H, c1L, c1_b, c2_w, c2_b, q);
}